// Round 1
// baseline (330.478 us; speedup 1.0000x reference)
//
#include <hip/hip_runtime.h>
#include <hip/hip_bf16.h>

#define BN 2
#define SDIM 2048
#define EDIM 1024
#define HN 16
#define DDIM 64

typedef __attribute__((ext_vector_type(8))) short bfrag;
typedef __attribute__((ext_vector_type(4))) float ffrag;

__device__ __forceinline__ ffrag mfma16(bfrag a, bfrag b, ffrag c) {
    return __builtin_amdgcn_mfma_f32_16x16x32_bf16(a, b, c, 0, 0, 0);
}

__device__ __forceinline__ ushort f2bf(float f) {
    union { float f; unsigned u; } un;
    un.f = f;
    unsigned u = un.u;
    u += 0x7fffu + ((u >> 16) & 1u);   // round-to-nearest-even
    return (ushort)(u >> 16);
}

// ---------------- convert fp32 -> bf16 (vectorized x4) ----------------
__global__ __launch_bounds__(256) void to_bf16(const float* __restrict__ in,
                                               ushort* __restrict__ out, int n) {
    int i = (blockIdx.x * 256 + threadIdx.x) * 4;
    if (i + 3 < n) {
        float4 v = *(const float4*)(in + i);
        ushort4 o;
        o.x = f2bf(v.x); o.y = f2bf(v.y); o.z = f2bf(v.z); o.w = f2bf(v.w);
        *(ushort4*)(out + i) = o;
    }
}

// ---------------- bf16 BT-GEMM: C[M,N] = A[M,K] * Bt[N,K]^T + bias ----------------
// MODE 0: plain fp32 output (row-major MxN), bias per col
// MODE 1: qkv scatter epilogue: col j -> (which,h,d), write bf16 to
//         qkv[which][(b*H+h)*S+s][d], q scaled by 1/sqrt(D)
template <int MODE>
__global__ __launch_bounds__(256) void gemm_bt(const ushort* __restrict__ A,
                                               const ushort* __restrict__ Bt,
                                               const float* __restrict__ bias,
                                               void* __restrict__ Cout,
                                               int M, int N, int K) {
    __shared__ ushort As[128][48];   // 32 cols + pad to 48 (96B stride, 16B aligned)
    __shared__ ushort Bs[128][48];

    const int tid  = threadIdx.x;
    const int wave = tid >> 6;
    const int lane = tid & 63;
    const int ln16 = lane & 15;
    const int quad = lane >> 4;
    const int wm = wave >> 1, wn = wave & 1;   // 2x2 wave grid, 64x64 each
    const int bm = blockIdx.x * 128;
    const int bn = blockIdx.y * 128;

    ffrag acc[4][4];
#pragma unroll
    for (int mi = 0; mi < 4; ++mi)
#pragma unroll
        for (int ni = 0; ni < 4; ++ni)
            acc[mi][ni] = (ffrag){0.f, 0.f, 0.f, 0.f};

    for (int k0 = 0; k0 < K; k0 += 32) {
#pragma unroll
        for (int p = 0; p < 2; ++p) {
            int idx = p * 256 + tid;          // 0..511
            int r = idx >> 2;                 // 128 rows
            int c = (idx & 3) * 8;            // 4 chunks of 8 bf16
            *(uint4*)&As[r][c] = *(const uint4*)(A + (size_t)(bm + r) * K + k0 + c);
            *(uint4*)&Bs[r][c] = *(const uint4*)(Bt + (size_t)(bn + r) * K + k0 + c);
        }
        __syncthreads();

        bfrag af[4], bf[4];
#pragma unroll
        for (int mi = 0; mi < 4; ++mi)
            af[mi] = *(const bfrag*)&As[wm * 64 + mi * 16 + ln16][quad * 8];
#pragma unroll
        for (int ni = 0; ni < 4; ++ni)
            bf[ni] = *(const bfrag*)&Bs[wn * 64 + ni * 16 + ln16][quad * 8];
#pragma unroll
        for (int mi = 0; mi < 4; ++mi)
#pragma unroll
            for (int ni = 0; ni < 4; ++ni)
                acc[mi][ni] = mfma16(af[mi], bf[ni], acc[mi][ni]);
        __syncthreads();
    }

    // epilogue: C/D layout col=lane&15, row=quad*4+reg
#pragma unroll
    for (int mi = 0; mi < 4; ++mi) {
#pragma unroll
        for (int ni = 0; ni < 4; ++ni) {
#pragma unroll
            for (int reg = 0; reg < 4; ++reg) {
                int row = bm + wm * 64 + mi * 16 + quad * 4 + reg;
                int col = bn + wn * 64 + ni * 16 + ln16;
                float v = acc[mi][ni][reg] + bias[col];
                if (MODE == 0) {
                    ((float*)Cout)[(size_t)row * N + col] = v;
                } else {
                    int which = col >> 10;        // 0=q 1=k 2=v
                    int rem = col & 1023;
                    int h = rem >> 6;
                    int d = rem & 63;
                    int b = row >> 11;            // token -> (b, s)
                    int s = row & 2047;
                    if (which == 0) v *= 0.125f;  // 1/sqrt(64)
                    size_t dst = (size_t)which * (BN * HN * SDIM * DDIM) +
                                 (((size_t)(b * HN + h)) * SDIM + s) * DDIM + d;
                    ((ushort*)Cout)[dst] = f2bf(v);
                }
            }
        }
    }
}

// ---------------- fused flash attention with distance decay ----------------
// grid: (S/64, B*H). block 256 = 4 waves. Each block: 64 query rows of one head.
__global__ __launch_bounds__(256) void flash_attn(const ushort* __restrict__ Qb,
                                                  const ushort* __restrict__ Kb,
                                                  const ushort* __restrict__ Vb,
                                                  const float* __restrict__ decay_ptr,
                                                  ushort* __restrict__ Ob) {
    __shared__ ushort Qs[64][72];
    __shared__ ushort Ks[64][72];
    __shared__ ushort Vts[64][72];   // V transposed: Vts[d][t]
    __shared__ ushort Pb[64][72];    // P tile bf16
    __shared__ float  Sf[64][65];    // fp32 scores
    __shared__ float  m_s[64], l_s[64], alpha_s[64];

    const int tid  = threadIdx.x;
    const int wave = tid >> 6;
    const int lane = tid & 63;
    const int ln16 = lane & 15;
    const int quad = lane >> 4;

    const int bh = blockIdx.y;
    const int q0 = blockIdx.x * 64;
    const size_t head_off = (size_t)bh * SDIM * DDIM;
    const float absa = fabsf(decay_ptr[0]);

    // stage Q tile (64 rows x 64 dims)
#pragma unroll
    for (int p = 0; p < 2; ++p) {
        int idx = p * 256 + tid;   // 0..511 = 64 rows x 8 chunks
        int r = idx >> 3;
        int c = (idx & 7) * 8;
        *(uint4*)&Qs[r][c] = *(const uint4*)(Qb + head_off + (size_t)(q0 + r) * DDIM + c);
    }
    if (tid < 64) { m_s[tid] = -1e30f; l_s[tid] = 0.f; }
    __syncthreads();

    bfrag aq[2];
#pragma unroll
    for (int kb = 0; kb < 2; ++kb)
        aq[kb] = *(const bfrag*)&Qs[wave * 16 + ln16][kb * 32 + quad * 8];

    ffrag o[4];
#pragma unroll
    for (int ni = 0; ni < 4; ++ni) o[ni] = (ffrag){0.f, 0.f, 0.f, 0.f};

    for (int t0 = 0; t0 < SDIM; t0 += 64) {
        // stage K tile + transposed V tile
#pragma unroll
        for (int p = 0; p < 2; ++p) {
            int idx = p * 256 + tid;
            int r = idx >> 3;
            int c = (idx & 7) * 8;
            *(uint4*)&Ks[r][c] = *(const uint4*)(Kb + head_off + (size_t)(t0 + r) * DDIM + c);
            uint4 vv = *(const uint4*)(Vb + head_off + (size_t)(t0 + r) * DDIM + c);
            ushort tmp[8];
            *(uint4*)tmp = vv;
#pragma unroll
            for (int i = 0; i < 8; ++i) Vts[c + i][r] = tmp[i];
        }
        __syncthreads();

        // S = Qs * Ks^T (Q pre-scaled by 1/sqrt(D)), multiply decay, to LDS fp32
#pragma unroll
        for (int ni = 0; ni < 4; ++ni) {
            ffrag acc = (ffrag){0.f, 0.f, 0.f, 0.f};
#pragma unroll
            for (int kb = 0; kb < 2; ++kb) {
                bfrag bk = *(const bfrag*)&Ks[ni * 16 + ln16][kb * 32 + quad * 8];
                acc = mfma16(aq[kb], bk, acc);
            }
            int col = ni * 16 + ln16;
            int kj = t0 + col;
#pragma unroll
            for (int reg = 0; reg < 4; ++reg) {
                int row = quad * 4 + reg;
                int qi = q0 + wave * 16 + row;
                float dec = __expf(-absa * fabsf((float)(qi - kj)));
                Sf[wave * 16 + row][col] = acc[reg] * dec;
            }
        }
        __syncthreads();

        // online softmax: 4 threads per row (same wave, adjacent lanes)
        {
            int r = tid >> 2;
            int part = tid & 3;
            float vals[16];
            float mx = -1e30f;
#pragma unroll
            for (int i = 0; i < 16; ++i) {
                vals[i] = Sf[r][part * 16 + i];
                mx = fmaxf(mx, vals[i]);
            }
            mx = fmaxf(mx, __shfl_xor(mx, 1));
            mx = fmaxf(mx, __shfl_xor(mx, 2));
            float mold = m_s[r];
            float mnew = fmaxf(mold, mx);
            float al = __expf(mold - mnew);
            float sum = 0.f;
#pragma unroll
            for (int i = 0; i < 16; ++i) {
                float p = __expf(vals[i] - mnew);
                sum += p;
                Pb[r][part * 16 + i] = f2bf(p);
            }
            sum += __shfl_xor(sum, 1);
            sum += __shfl_xor(sum, 2);
            if (part == 0) {
                l_s[r] = l_s[r] * al + sum;
                m_s[r] = mnew;
                alpha_s[r] = al;
            }
        }
        __syncthreads();

        // O = O*alpha + P @ V
        float alr[4];
#pragma unroll
        for (int reg = 0; reg < 4; ++reg) alr[reg] = alpha_s[wave * 16 + quad * 4 + reg];
        bfrag ap[2];
#pragma unroll
        for (int kb = 0; kb < 2; ++kb)
            ap[kb] = *(const bfrag*)&Pb[wave * 16 + ln16][kb * 32 + quad * 8];
#pragma unroll
        for (int ni = 0; ni < 4; ++ni) {
#pragma unroll
            for (int reg = 0; reg < 4; ++reg) o[ni][reg] *= alr[reg];
#pragma unroll
            for (int kb = 0; kb < 2; ++kb) {
                bfrag bv = *(const bfrag*)&Vts[ni * 16 + ln16][kb * 32 + quad * 8];
                o[ni] = mfma16(ap[kb], bv, o[ni]);
            }
        }
        __syncthreads();
    }

    // epilogue: O /= l, write (B,S,E) bf16
    const int b = bh / HN, h = bh % HN;
#pragma unroll
    for (int ni = 0; ni < 4; ++ni) {
#pragma unroll
        for (int reg = 0; reg < 4; ++reg) {
            int row = wave * 16 + quad * 4 + reg;
            float val = o[ni][reg] / l_s[row];
            int s = q0 + row;
            int e = h * DDIM + ni * 16 + ln16;
            Ob[((size_t)(b * SDIM + s)) * EDIM + e] = f2bf(val);
        }
    }
}

extern "C" void kernel_launch(void* const* d_in, const int* in_sizes, int n_in,
                              void* d_out, int out_size, void* d_ws, size_t ws_size,
                              hipStream_t stream) {
    const float* x      = (const float*)d_in[0];
    const float* Wqkv_w = (const float*)d_in[1];
    const float* Wqkv_b = (const float*)d_in[2];
    const float* out_w  = (const float*)d_in[3];
    const float* out_b  = (const float*)d_in[4];
    const float* dd     = (const float*)d_in[5];

    char* ws = (char*)d_ws;
    const size_t MB = 1024 * 1024;
    ushort* xb    = (ushort*)(ws + 0 * MB);    // 4096x1024 bf16 = 8 MB
    ushort* wqkvb = (ushort*)(ws + 8 * MB);    // 3072x1024 bf16 = 6 MB
    ushort* owb   = (ushort*)(ws + 14 * MB);   // 1024x1024 bf16 = 2 MB
    ushort* qkvb  = (ushort*)(ws + 16 * MB);   // 3 x (B*H*S*D) bf16 = 24 MB
    ushort* ob    = (ushort*)(ws + 40 * MB);   // 4096x1024 bf16 = 8 MB

    const int n_x = BN * SDIM * EDIM;          // 4194304
    const int n_w = 3 * EDIM * EDIM;           // 3145728
    const int n_o = EDIM * EDIM;               // 1048576
    const int HSD = BN * HN * SDIM * DDIM;     // 4194304 per q/k/v

    to_bf16<<<n_x / 1024, 256, 0, stream>>>(x, xb, n_x);
    to_bf16<<<n_w / 1024, 256, 0, stream>>>(Wqkv_w, wqkvb, n_w);
    to_bf16<<<n_o / 1024, 256, 0, stream>>>(out_w, owb, n_o);

    // QKV projection with scatter epilogue
    gemm_bt<1><<<dim3(32, 24), 256, 0, stream>>>(xb, wqkvb, Wqkv_b, (void*)qkvb,
                                                 BN * SDIM, 3 * EDIM, EDIM);

    // fused attention
    flash_attn<<<dim3(SDIM / 64, BN * HN), 256, 0, stream>>>(
        qkvb, qkvb + HSD, qkvb + 2 * HSD, dd, ob);

    // output projection -> fp32 d_out
    gemm_bt<0><<<dim3(32, 8), 256, 0, stream>>>(ob, owb, out_b, d_out,
                                                BN * SDIM, EDIM, EDIM);
}

// Round 2
// 329.545 us; speedup vs baseline: 1.0028x; 1.0028x over previous
//
#include <hip/hip_runtime.h>
#include <hip/hip_bf16.h>

#define BN 2
#define SDIM 2048
#define EDIM 1024
#define HN 16
#define DDIM 64

typedef __attribute__((ext_vector_type(8))) short bfrag;
typedef __attribute__((ext_vector_type(4))) float ffrag;

__device__ __forceinline__ ffrag mfma16(bfrag a, bfrag b, ffrag c) {
    return __builtin_amdgcn_mfma_f32_16x16x32_bf16(a, b, c, 0, 0, 0);
}

__device__ __forceinline__ ushort f2bf(float f) {
    union { float f; unsigned u; } un;
    un.f = f;
    unsigned u = un.u;
    u += 0x7fffu + ((u >> 16) & 1u);   // round-to-nearest-even
    return (ushort)(u >> 16);
}

// ---------------- convert fp32 -> bf16 (vectorized x4) ----------------
__global__ __launch_bounds__(256) void to_bf16(const float* __restrict__ in,
                                               ushort* __restrict__ out, int n) {
    int i = (blockIdx.x * 256 + threadIdx.x) * 4;
    if (i + 3 < n) {
        float4 v = *(const float4*)(in + i);
        ushort4 o;
        o.x = f2bf(v.x); o.y = f2bf(v.y); o.z = f2bf(v.z); o.w = f2bf(v.w);
        *(ushort4*)(out + i) = o;
    }
}

// ---------------- bf16 BT-GEMM: C[M,N] = A[M,K] * Bt[N,K]^T + bias ----------------
// MODE 0: plain fp32 output (row-major MxN), bias per col
// MODE 1: qkv scatter epilogue: col j -> (which,h,d); Q,K to [b,h,s,d],
//         V to TRANSPOSED [b,h,d,s]; q scaled by 1/sqrt(D). All bf16.
template <int MODE>
__global__ __launch_bounds__(256) void gemm_bt(const ushort* __restrict__ A,
                                               const ushort* __restrict__ Bt,
                                               const float* __restrict__ bias,
                                               void* __restrict__ Cout,
                                               int M, int N, int K) {
    __shared__ ushort As[128][48];   // 32 cols + pad to 48 (96B stride)
    __shared__ ushort Bs[128][48];

    const int tid  = threadIdx.x;
    const int wave = tid >> 6;
    const int lane = tid & 63;
    const int ln16 = lane & 15;
    const int quad = lane >> 4;
    const int wm = wave >> 1, wn = wave & 1;   // 2x2 wave grid, 64x64 each
    const int bm = blockIdx.x * 128;
    const int bn = blockIdx.y * 128;

    ffrag acc[4][4];
#pragma unroll
    for (int mi = 0; mi < 4; ++mi)
#pragma unroll
        for (int ni = 0; ni < 4; ++ni)
            acc[mi][ni] = (ffrag){0.f, 0.f, 0.f, 0.f};

    for (int k0 = 0; k0 < K; k0 += 32) {
#pragma unroll
        for (int p = 0; p < 2; ++p) {
            int idx = p * 256 + tid;          // 0..511
            int r = idx >> 2;                 // 128 rows
            int c = (idx & 3) * 8;            // 4 chunks of 8 bf16
            *(uint4*)&As[r][c] = *(const uint4*)(A + (size_t)(bm + r) * K + k0 + c);
            *(uint4*)&Bs[r][c] = *(const uint4*)(Bt + (size_t)(bn + r) * K + k0 + c);
        }
        __syncthreads();

        bfrag af[4], bf[4];
#pragma unroll
        for (int mi = 0; mi < 4; ++mi)
            af[mi] = *(const bfrag*)&As[wm * 64 + mi * 16 + ln16][quad * 8];
#pragma unroll
        for (int ni = 0; ni < 4; ++ni)
            bf[ni] = *(const bfrag*)&Bs[wn * 64 + ni * 16 + ln16][quad * 8];
#pragma unroll
        for (int mi = 0; mi < 4; ++mi)
#pragma unroll
            for (int ni = 0; ni < 4; ++ni)
                acc[mi][ni] = mfma16(af[mi], bf[ni], acc[mi][ni]);
        __syncthreads();
    }

    // epilogue: C/D layout col=lane&15, row=quad*4+reg
#pragma unroll
    for (int mi = 0; mi < 4; ++mi) {
#pragma unroll
        for (int ni = 0; ni < 4; ++ni) {
#pragma unroll
            for (int reg = 0; reg < 4; ++reg) {
                int row = bm + wm * 64 + mi * 16 + quad * 4 + reg;
                int col = bn + wn * 64 + ni * 16 + ln16;
                float v = acc[mi][ni][reg] + bias[col];
                if (MODE == 0) {
                    ((float*)Cout)[(size_t)row * N + col] = v;
                } else {
                    int which = col >> 10;        // 0=q 1=k 2=v
                    int rem = col & 1023;
                    int h = rem >> 6;
                    int d = rem & 63;
                    int b = row >> 11;            // token -> (b, s)
                    int s = row & 2047;
                    if (which == 0) v *= 0.125f;  // 1/sqrt(64)
                    size_t dst;
                    if (which == 2) {
                        // V transposed: [b,h,d,s]
                        dst = 2ull * (BN * HN * SDIM * DDIM) +
                              (((size_t)(b * HN + h)) * DDIM + d) * SDIM + s;
                    } else {
                        dst = (size_t)which * (BN * HN * SDIM * DDIM) +
                              (((size_t)(b * HN + h)) * SDIM + s) * DDIM + d;
                    }
                    ((ushort*)Cout)[dst] = f2bf(v);
                }
            }
        }
    }
}

// ---------------- fused flash attention with distance decay ----------------
// grid: (S/64, B*H). block 256 = 4 waves. Each block: 64 query rows of one head.
// V input is pre-transposed [b,h,d,s]. Softmax fully in registers (quad shuffles).
__global__ __launch_bounds__(256) void flash_attn(const ushort* __restrict__ Qb,
                                                  const ushort* __restrict__ Kb,
                                                  const ushort* __restrict__ Vtb,
                                                  const float* __restrict__ decay_ptr,
                                                  ushort* __restrict__ Ob) {
    __shared__ ushort Qs[64][72];
    __shared__ ushort Ks[64][72];
    __shared__ ushort Vts[64][72];   // Vt tile: rows d, cols t (loaded directly)
    __shared__ ushort Pb[64][72];    // P tile bf16 (C-layout -> A-layout exchange)

    const int tid  = threadIdx.x;
    const int wave = tid >> 6;
    const int lane = tid & 63;
    const int ln16 = lane & 15;
    const int quad = lane >> 4;

    const int bh = blockIdx.y;
    const int q0 = blockIdx.x * 64;
    const size_t head_off = (size_t)bh * SDIM * DDIM;
    const float absa = fabsf(decay_ptr[0]);

    // stage Q tile (64 rows x 64 dims)
#pragma unroll
    for (int p = 0; p < 2; ++p) {
        int idx = p * 256 + tid;   // 0..511 = 64 rows x 8 chunks
        int r = idx >> 3;
        int c = (idx & 7) * 8;
        *(uint4*)&Qs[r][c] = *(const uint4*)(Qb + head_off + (size_t)(q0 + r) * DDIM + c);
    }
    __syncthreads();

    bfrag aq[2];
#pragma unroll
    for (int kb = 0; kb < 2; ++kb)
        aq[kb] = *(const bfrag*)&Qs[wave * 16 + ln16][kb * 32 + quad * 8];

    // per-thread fixed row/col indices within the 64x64 tile
    int rl[4], cl[4];
#pragma unroll
    for (int reg = 0; reg < 4; ++reg) rl[reg] = wave * 16 + quad * 4 + reg;
#pragma unroll
    for (int ni = 0; ni < 4; ++ni) cl[ni] = ni * 16 + ln16;

    // decay partial factors (both <= 1, precomputed once)
    float Rfac[4], Cfac[4];
#pragma unroll
    for (int reg = 0; reg < 4; ++reg) Rfac[reg] = __expf(-absa * (float)(63 - rl[reg]));
#pragma unroll
    for (int ni = 0; ni < 4; ++ni) Cfac[ni] = __expf(-absa * (float)(63 - cl[ni]));

    float m_r[4], l_r[4];
#pragma unroll
    for (int reg = 0; reg < 4; ++reg) { m_r[reg] = -1e30f; l_r[reg] = 0.f; }

    ffrag o[4];
#pragma unroll
    for (int ni = 0; ni < 4; ++ni) o[ni] = (ffrag){0.f, 0.f, 0.f, 0.f};

    for (int t0 = 0; t0 < SDIM; t0 += 64) {
        // stage K tile [t][d] and Vt tile [d][t] (both coalesced, no transpose)
#pragma unroll
        for (int p = 0; p < 2; ++p) {
            int idx = p * 256 + tid;
            int r = idx >> 3;
            int c = (idx & 7) * 8;
            *(uint4*)&Ks[r][c]  = *(const uint4*)(Kb  + head_off + (size_t)(t0 + r) * DDIM + c);
            *(uint4*)&Vts[r][c] = *(const uint4*)(Vtb + head_off + (size_t)r * SDIM + t0 + c);
        }
        __syncthreads();

        // S = Qs * Ks^T  (Q pre-scaled by 1/sqrt(D))
        ffrag sc[4];
#pragma unroll
        for (int ni = 0; ni < 4; ++ni) {
            ffrag a = (ffrag){0.f, 0.f, 0.f, 0.f};
#pragma unroll
            for (int kb = 0; kb < 2; ++kb) {
                bfrag bk = *(const bfrag*)&Ks[ni * 16 + ln16][kb * 32 + quad * 8];
                a = mfma16(aq[kb], bk, a);
            }
            sc[ni] = a;
        }

        // multiplicative distance decay, factored per tile
        int base = q0 - t0;   // multiple of 64
        if (base > 0) {
            // dist = base + rl - cl = (base + rl - 63) + (63 - cl), both >= 0
#pragma unroll
            for (int reg = 0; reg < 4; ++reg) {
                float E = __expf(-absa * (float)(base + rl[reg] - 63));
#pragma unroll
                for (int ni = 0; ni < 4; ++ni)
                    sc[ni][reg] *= E * Cfac[ni];
            }
        } else if (base < 0) {
            // dist = -base + cl - rl = (-base + cl - 63) + (63 - rl), both >= 0
#pragma unroll
            for (int ni = 0; ni < 4; ++ni) {
                float F = __expf(-absa * (float)(-base + cl[ni] - 63));
#pragma unroll
                for (int reg = 0; reg < 4; ++reg)
                    sc[ni][reg] *= F * Rfac[reg];
            }
        } else {
            // diagonal tile: per-element
#pragma unroll
            for (int ni = 0; ni < 4; ++ni)
#pragma unroll
                for (int reg = 0; reg < 4; ++reg)
                    sc[ni][reg] *= __expf(-absa * fabsf((float)(rl[reg] - cl[ni])));
        }

        // online softmax fully in registers: row r lives in the 16 lanes of a quad
        float alpha[4];
#pragma unroll
        for (int reg = 0; reg < 4; ++reg) {
            float mx = fmaxf(fmaxf(sc[0][reg], sc[1][reg]), fmaxf(sc[2][reg], sc[3][reg]));
            mx = fmaxf(mx, __shfl_xor(mx, 1));
            mx = fmaxf(mx, __shfl_xor(mx, 2));
            mx = fmaxf(mx, __shfl_xor(mx, 4));
            mx = fmaxf(mx, __shfl_xor(mx, 8));
            float mnew = fmaxf(m_r[reg], mx);
            alpha[reg] = __expf(m_r[reg] - mnew);
            m_r[reg] = mnew;
            float sum = 0.f;
#pragma unroll
            for (int ni = 0; ni < 4; ++ni) {
                float p = __expf(sc[ni][reg] - mnew);
                sum += p;
                sc[ni][reg] = p;
            }
            sum += __shfl_xor(sum, 1);
            sum += __shfl_xor(sum, 2);
            sum += __shfl_xor(sum, 4);
            sum += __shfl_xor(sum, 8);
            l_r[reg] = l_r[reg] * alpha[reg] + sum;
        }

        // P (C-layout) -> LDS bf16; each wave only touches its own 16 rows,
        // so no barrier needed between write and A-layout read (same wave,
        // compiler inserts lgkmcnt wait).
#pragma unroll
        for (int ni = 0; ni < 4; ++ni)
#pragma unroll
            for (int reg = 0; reg < 4; ++reg)
                Pb[rl[reg]][cl[ni]] = f2bf(sc[ni][reg]);

        bfrag ap[2];
#pragma unroll
        for (int kb = 0; kb < 2; ++kb)
            ap[kb] = *(const bfrag*)&Pb[wave * 16 + ln16][kb * 32 + quad * 8];

        // O = O*alpha + P @ V
#pragma unroll
        for (int ni = 0; ni < 4; ++ni) {
#pragma unroll
            for (int reg = 0; reg < 4; ++reg) o[ni][reg] *= alpha[reg];
#pragma unroll
            for (int kb = 0; kb < 2; ++kb) {
                bfrag bv = *(const bfrag*)&Vts[ni * 16 + ln16][kb * 32 + quad * 8];
                o[ni] = mfma16(ap[kb], bv, o[ni]);
            }
        }
        __syncthreads();
    }

    // epilogue: O /= l, write (B,S,E) bf16
    const int b = bh / HN, h = bh % HN;
#pragma unroll
    for (int ni = 0; ni < 4; ++ni) {
#pragma unroll
        for (int reg = 0; reg < 4; ++reg) {
            float val = o[ni][reg] / l_r[reg];
            int s = q0 + rl[reg];
            int e = h * DDIM + cl[ni];
            Ob[((size_t)(b * SDIM + s)) * EDIM + e] = f2bf(val);
        }
    }
}

extern "C" void kernel_launch(void* const* d_in, const int* in_sizes, int n_in,
                              void* d_out, int out_size, void* d_ws, size_t ws_size,
                              hipStream_t stream) {
    const float* x      = (const float*)d_in[0];
    const float* Wqkv_w = (const float*)d_in[1];
    const float* Wqkv_b = (const float*)d_in[2];
    const float* out_w  = (const float*)d_in[3];
    const float* out_b  = (const float*)d_in[4];
    const float* dd     = (const float*)d_in[5];

    char* ws = (char*)d_ws;
    const size_t MB = 1024 * 1024;
    ushort* xb    = (ushort*)(ws + 0 * MB);    // 4096x1024 bf16 = 8 MB
    ushort* wqkvb = (ushort*)(ws + 8 * MB);    // 3072x1024 bf16 = 6 MB
    ushort* owb   = (ushort*)(ws + 14 * MB);   // 1024x1024 bf16 = 2 MB
    ushort* qkvb  = (ushort*)(ws + 16 * MB);   // q,k:[b,h,s,d] v:[b,h,d,s] = 24 MB
    ushort* ob    = (ushort*)(ws + 40 * MB);   // 4096x1024 bf16 = 8 MB

    const int n_x = BN * SDIM * EDIM;          // 4194304
    const int n_w = 3 * EDIM * EDIM;           // 3145728
    const int n_o = EDIM * EDIM;               // 1048576
    const int HSD = BN * HN * SDIM * DDIM;     // 4194304 per q/k/v

    to_bf16<<<n_x / 1024, 256, 0, stream>>>(x, xb, n_x);
    to_bf16<<<n_w / 1024, 256, 0, stream>>>(Wqkv_w, wqkvb, n_w);
    to_bf16<<<n_o / 1024, 256, 0, stream>>>(out_w, owb, n_o);

    // QKV projection with scatter epilogue (V written transposed)
    gemm_bt<1><<<dim3(32, 24), 256, 0, stream>>>(xb, wqkvb, Wqkv_b, (void*)qkvb,
                                                 BN * SDIM, 3 * EDIM, EDIM);

    // fused attention
    flash_attn<<<dim3(SDIM / 64, BN * HN), 256, 0, stream>>>(
        qkvb, qkvb + HSD, qkvb + 2 * HSD, dd, ob);

    // output projection -> fp32 d_out
    gemm_bt<0><<<dim3(32, 8), 256, 0, stream>>>(ob, owb, out_b, d_out,
                                                BN * SDIM, EDIM, EDIM);
}

// Round 3
// 305.635 us; speedup vs baseline: 1.0813x; 1.0782x over previous
//
#include <hip/hip_runtime.h>
#include <hip/hip_bf16.h>

#define BN 2
#define SDIM 2048
#define EDIM 1024
#define HN 16
#define DDIM 64

typedef __attribute__((ext_vector_type(8))) short bfrag;
typedef __attribute__((ext_vector_type(4))) float ffrag;

__device__ __forceinline__ ffrag mfma16(bfrag a, bfrag b, ffrag c) {
    return __builtin_amdgcn_mfma_f32_16x16x32_bf16(a, b, c, 0, 0, 0);
}

__device__ __forceinline__ ushort f2bf(float f) {
    union { float f; unsigned u; } un;
    un.f = f;
    unsigned u = un.u;
    u += 0x7fffu + ((u >> 16) & 1u);   // RNE
    return (ushort)(u >> 16);
}

// pack two floats -> one uint holding two bf16 (v_cvt_pk_bf16_f32 path)
__device__ __forceinline__ uint pkbf2(float a, float b) {
    __hip_bfloat162 h = __float22bfloat162_rn(make_float2(a, b));
    union { __hip_bfloat162 h; uint u; } cv;
    cv.h = h;
    return cv.u;
}

// async global->LDS 16B per lane (dest = wave-uniform base + lane*16)
__device__ __forceinline__ void gld16(const void* g, void* l) {
    __builtin_amdgcn_global_load_lds((const __attribute__((address_space(1))) void*)g,
                                     (__attribute__((address_space(3))) void*)l,
                                     16, 0, 0);
}

// ---------------- fused fp32 -> bf16 conversion for all three inputs ----------------
__global__ __launch_bounds__(256) void to_bf16_3(const float* __restrict__ a, ushort* __restrict__ oa, int na,
                                                 const float* __restrict__ b, ushort* __restrict__ ob, int nb,
                                                 const float* __restrict__ c, ushort* __restrict__ oc, int nc) {
    int i = (blockIdx.x * 256 + threadIdx.x) * 4;
    const float* src;
    ushort* dst;
    if (i < na)              { src = a + i;            dst = oa + i; }
    else if (i < na + nb)    { src = b + (i - na);     dst = ob + (i - na); }
    else if (i < na + nb + nc) { src = c + (i - na - nb); dst = oc + (i - na - nb); }
    else return;
    float4 v = *(const float4*)src;
    uint2 u;
    u.x = pkbf2(v.x, v.y);
    u.y = pkbf2(v.z, v.w);
    *(uint2*)dst = u;
}

// ---------------- bf16 BT-GEMM: C[M,N] = A[M,K] * Bt[N,K]^T + bias ----------------
// Staging via global_load_lds width=16 into unpadded [128][32] (m97 structure).
// MODE 0: fp32 output row-major; MODE 1: qkv scatter (V transposed to [b,h,d,s])
template <int MODE>
__global__ __launch_bounds__(256) void gemm_bt(const ushort* __restrict__ A,
                                               const ushort* __restrict__ Bt,
                                               const float* __restrict__ bias,
                                               void* __restrict__ Cout,
                                               int M, int N, int K) {
    __shared__ ushort As[128][32];   // unpadded: LDS offset = chunk*16 (lane-contiguous)
    __shared__ ushort Bs[128][32];

    const int tid  = threadIdx.x;
    const int wave = tid >> 6;
    const int lane = tid & 63;
    const int ln16 = lane & 15;
    const int quad = lane >> 4;
    const int wm = wave >> 1, wn = wave & 1;
    const int bm = blockIdx.x * 128;
    const int bn = blockIdx.y * 128;

    ffrag acc[4][4];
#pragma unroll
    for (int mi = 0; mi < 4; ++mi)
#pragma unroll
        for (int ni = 0; ni < 4; ++ni)
            acc[mi][ni] = (ffrag){0.f, 0.f, 0.f, 0.f};

    for (int k0 = 0; k0 < K; k0 += 32) {
#pragma unroll
        for (int p = 0; p < 2; ++p) {
            int chunk = p * 256 + tid;       // 0..511 16B chunks
            int r = chunk >> 2;              // 128 rows
            int c = (chunk & 3) * 8;         // 4 chunks of 8 bf16
            gld16(A  + (size_t)(bm + r) * K + k0 + c, &As[r][c]);
            gld16(Bt + (size_t)(bn + r) * K + k0 + c, &Bs[r][c]);
        }
        __syncthreads();   // drains vmcnt -> LDS valid

        bfrag af[4], bf[4];
#pragma unroll
        for (int mi = 0; mi < 4; ++mi)
            af[mi] = *(const bfrag*)&As[wm * 64 + mi * 16 + ln16][quad * 8];
#pragma unroll
        for (int ni = 0; ni < 4; ++ni)
            bf[ni] = *(const bfrag*)&Bs[wn * 64 + ni * 16 + ln16][quad * 8];
#pragma unroll
        for (int mi = 0; mi < 4; ++mi)
#pragma unroll
            for (int ni = 0; ni < 4; ++ni)
                acc[mi][ni] = mfma16(af[mi], bf[ni], acc[mi][ni]);
        __syncthreads();
    }

    // epilogue: C/D layout col=lane&15, row=quad*4+reg
#pragma unroll
    for (int mi = 0; mi < 4; ++mi) {
#pragma unroll
        for (int ni = 0; ni < 4; ++ni) {
#pragma unroll
            for (int reg = 0; reg < 4; ++reg) {
                int row = bm + wm * 64 + mi * 16 + quad * 4 + reg;
                int col = bn + wn * 64 + ni * 16 + ln16;
                float v = acc[mi][ni][reg] + bias[col];
                if (MODE == 0) {
                    ((float*)Cout)[(size_t)row * N + col] = v;
                } else {
                    int which = col >> 10;        // 0=q 1=k 2=v
                    int rem = col & 1023;
                    int h = rem >> 6;
                    int d = rem & 63;
                    int b = row >> 11;
                    int s = row & 2047;
                    if (which == 0) v *= 0.125f;  // 1/sqrt(64)
                    size_t dst;
                    if (which == 2) {
                        dst = 2ull * (BN * HN * SDIM * DDIM) +
                              (((size_t)(b * HN + h)) * DDIM + d) * SDIM + s;
                    } else {
                        dst = (size_t)which * (BN * HN * SDIM * DDIM) +
                              (((size_t)(b * HN + h)) * SDIM + s) * DDIM + d;
                    }
                    ((ushort*)Cout)[dst] = f2bf(v);
                }
            }
        }
    }
}

// ---------------- fused flash attention, fixed-max softmax, swapped MFMA ----------------
// grid (S/64, B*H), 256 threads = 4 waves; wave handles 16 query rows (m = lane&15).
// All per-lane score data belongs to ONE query row -> no cross-lane softmax work.
__global__ __launch_bounds__(256) void flash_attn(const ushort* __restrict__ Qb,
                                                  const ushort* __restrict__ Kb,
                                                  const ushort* __restrict__ Vtb,
                                                  const float* __restrict__ decay_ptr,
                                                  ushort* __restrict__ Ob) {
    __shared__ ushort Qs[64][72];
    __shared__ ushort Ks[64][72];
    __shared__ ushort Vts[64][72];   // Vt tile [d][t]
    __shared__ ushort Pb[64][72];    // P[m][t] bf16

    const int tid  = threadIdx.x;
    const int wave = tid >> 6;
    const int lane = tid & 63;
    const int ln16 = lane & 15;
    const int quad = lane >> 4;

    const int bh = blockIdx.y;
    const int q0 = blockIdx.x * 64;
    const size_t head_off = (size_t)bh * SDIM * DDIM;
    const float absa = fabsf(decay_ptr[0]);
    const float LOG2E = 1.442695041f;
    const float M0L2 = -17.3123404f;   // -12 * log2(e)

    // stage Q tile
#pragma unroll
    for (int p = 0; p < 2; ++p) {
        int idx = p * 256 + tid;
        int r = idx >> 3;
        int c = (idx & 7) * 8;
        *(uint4*)&Qs[r][c] = *(const uint4*)(Qb + head_off + (size_t)(q0 + r) * DDIM + c);
    }
    __syncthreads();

    bfrag aq[2];
#pragma unroll
    for (int kb = 0; kb < 2; ++kb)
        aq[kb] = *(const bfrag*)&Qs[wave * 16 + ln16][kb * 32 + quad * 8];

    const int rw = wave * 16 + ln16;   // query row within 64-block (one per lane)

    // decay tables (precomputed once; include log2e so p = exp2(fma(s,f,M0L2)))
    float Er = __expf(-absa * (float)rw);          // exp(-a*rw)
    float Fr = __expf(-absa * (float)(63 - rw));   // exp(-a*(63-rw))
    float Ec[4][4], Fc[4][4];
#pragma unroll
    for (int ni = 0; ni < 4; ++ni)
#pragma unroll
        for (int reg = 0; reg < 4; ++reg) {
            int c = ni * 16 + quad * 4 + reg;
            Ec[ni][reg] = __expf(-absa * (float)(63 - c));
            Fc[ni][reg] = __expf(-absa * (float)c);
        }

    float l = 0.f;
    ffrag o[4];
#pragma unroll
    for (int ni = 0; ni < 4; ++ni) o[ni] = (ffrag){0.f, 0.f, 0.f, 0.f};

    for (int t0 = 0; t0 < SDIM; t0 += 64) {
#pragma unroll
        for (int p = 0; p < 2; ++p) {
            int idx = p * 256 + tid;
            int r = idx >> 3;
            int c = (idx & 7) * 8;
            *(uint4*)&Ks[r][c]  = *(const uint4*)(Kb  + head_off + (size_t)(t0 + r) * DDIM + c);
            *(uint4*)&Vts[r][c] = *(const uint4*)(Vtb + head_off + (size_t)r * SDIM + t0 + c);
        }
        __syncthreads();

        // S^T = K * Q^T : sc[ni][reg] = S[m=ln16][t = t0 + ni*16 + quad*4 + reg]
        ffrag sc[4];
#pragma unroll
        for (int ni = 0; ni < 4; ++ni) {
            ffrag a = (ffrag){0.f, 0.f, 0.f, 0.f};
#pragma unroll
            for (int kb = 0; kb < 2; ++kb) {
                bfrag ak = *(const bfrag*)&Ks[ni * 16 + ln16][kb * 32 + quad * 8];
                a = mfma16(ak, aq[kb], a);
            }
            sc[ni] = a;
        }

        // decay factor f (times log2e), then p = exp2(sc*f + M0L2), accumulate l,
        // pack P to LDS as b64 writes.
        const int base = q0 - t0;
        float h0;
        if (base > 0)      h0 = __expf(-absa * (float)(base - 63)) * Er * LOG2E;
        else if (base < 0) h0 = __expf(-absa * (float)(-base - 63)) * Fr * LOG2E;
        else               h0 = 0.f;  // unused on diagonal

#pragma unroll
        for (int ni = 0; ni < 4; ++ni) {
            float p0, p1, p2, p3;
            if (base > 0) {
                p0 = exp2f(fmaf(sc[ni][0], h0 * Ec[ni][0], M0L2));
                p1 = exp2f(fmaf(sc[ni][1], h0 * Ec[ni][1], M0L2));
                p2 = exp2f(fmaf(sc[ni][2], h0 * Ec[ni][2], M0L2));
                p3 = exp2f(fmaf(sc[ni][3], h0 * Ec[ni][3], M0L2));
            } else if (base < 0) {
                p0 = exp2f(fmaf(sc[ni][0], h0 * Fc[ni][0], M0L2));
                p1 = exp2f(fmaf(sc[ni][1], h0 * Fc[ni][1], M0L2));
                p2 = exp2f(fmaf(sc[ni][2], h0 * Fc[ni][2], M0L2));
                p3 = exp2f(fmaf(sc[ni][3], h0 * Fc[ni][3], M0L2));
            } else {
#pragma unroll
                for (int reg = 0; reg < 4; ++reg) {
                    int c = ni * 16 + quad * 4 + reg;
                    float dec = __expf(-absa * fabsf((float)(rw - c))) * LOG2E;
                    sc[ni][reg] = exp2f(fmaf(sc[ni][reg], dec, M0L2));
                }
                p0 = sc[ni][0]; p1 = sc[ni][1]; p2 = sc[ni][2]; p3 = sc[ni][3];
            }
            l += (p0 + p1) + (p2 + p3);
            uint2 pk;
            pk.x = pkbf2(p0, p1);
            pk.y = pkbf2(p2, p3);
            *(uint2*)&Pb[rw][ni * 16 + quad * 4] = pk;   // 8B store, ~2-way banks (free)
        }

        // same-wave LDS RAW: compiler inserts lgkmcnt wait; no barrier needed
        bfrag ap[2];
#pragma unroll
        for (int kb = 0; kb < 2; ++kb)
            ap[kb] = *(const bfrag*)&Pb[rw][kb * 32 + quad * 8];

        // O^T = V^T * P^T : o[ni] accumulates O[m=ln16][d = ni*16 + quad*4 + reg]
#pragma unroll
        for (int ni = 0; ni < 4; ++ni) {
#pragma unroll
            for (int kb = 0; kb < 2; ++kb) {
                bfrag av = *(const bfrag*)&Vts[ni * 16 + ln16][kb * 32 + quad * 8];
                o[ni] = mfma16(av, ap[kb], o[ni]);
            }
        }
        __syncthreads();
    }

    // final l reduction: quads hold disjoint key-partials of row m=ln16
    l += __shfl_xor(l, 16);
    l += __shfl_xor(l, 32);
    float inv = 1.f / l;

    // write O: lane's 16 values all in row s = q0+rw, dims 4-consecutive per frag
    const int b = bh / HN, h = bh % HN;
    const int s = q0 + rw;
    ushort* dst = Ob + ((size_t)(b * SDIM + s)) * EDIM + h * DDIM + quad * 4;
#pragma unroll
    for (int ni = 0; ni < 4; ++ni) {
        uint2 pk;
        pk.x = pkbf2(o[ni][0] * inv, o[ni][1] * inv);
        pk.y = pkbf2(o[ni][2] * inv, o[ni][3] * inv);
        *(uint2*)(dst + ni * 16) = pk;
    }
}

extern "C" void kernel_launch(void* const* d_in, const int* in_sizes, int n_in,
                              void* d_out, int out_size, void* d_ws, size_t ws_size,
                              hipStream_t stream) {
    const float* x      = (const float*)d_in[0];
    const float* Wqkv_w = (const float*)d_in[1];
    const float* Wqkv_b = (const float*)d_in[2];
    const float* out_w  = (const float*)d_in[3];
    const float* out_b  = (const float*)d_in[4];
    const float* dd     = (const float*)d_in[5];

    char* ws = (char*)d_ws;
    const size_t MB = 1024 * 1024;
    ushort* xb    = (ushort*)(ws + 0 * MB);
    ushort* wqkvb = (ushort*)(ws + 8 * MB);
    ushort* owb   = (ushort*)(ws + 14 * MB);
    ushort* qkvb  = (ushort*)(ws + 16 * MB);   // q,k:[b,h,s,d] v:[b,h,d,s]
    ushort* ob    = (ushort*)(ws + 40 * MB);

    const int n_x = BN * SDIM * EDIM;
    const int n_w = 3 * EDIM * EDIM;
    const int n_o = EDIM * EDIM;
    const int HSD = BN * HN * SDIM * DDIM;

    to_bf16_3<<<(n_x + n_w + n_o) / 1024, 256, 0, stream>>>(
        x, xb, n_x, Wqkv_w, wqkvb, n_w, out_w, owb, n_o);

    gemm_bt<1><<<dim3(32, 24), 256, 0, stream>>>(xb, wqkvb, Wqkv_b, (void*)qkvb,
                                                 BN * SDIM, 3 * EDIM, EDIM);

    flash_attn<<<dim3(SDIM / 64, BN * HN), 256, 0, stream>>>(
        qkvb, qkvb + HSD, qkvb + 2 * HSD, dd, ob);

    gemm_bt<0><<<dim3(32, 8), 256, 0, stream>>>(ob, owb, out_b, d_out,
                                                BN * SDIM, EDIM, EDIM);
}

// Round 4
// 238.745 us; speedup vs baseline: 1.3842x; 1.2802x over previous
//
#include <hip/hip_runtime.h>
#include <hip/hip_bf16.h>

#define BN 2
#define SDIM 2048
#define EDIM 1024
#define HN 16
#define DDIM 64

typedef __attribute__((ext_vector_type(8))) short bfrag;
typedef __attribute__((ext_vector_type(4))) float ffrag;

__device__ __forceinline__ ffrag mfma16(bfrag a, bfrag b, ffrag c) {
    return __builtin_amdgcn_mfma_f32_16x16x32_bf16(a, b, c, 0, 0, 0);
}

__device__ __forceinline__ ushort f2bf(float f) {
    union { float f; unsigned u; } un;
    un.f = f;
    unsigned u = un.u;
    u += 0x7fffu + ((u >> 16) & 1u);   // RNE
    return (ushort)(u >> 16);
}

__device__ __forceinline__ uint pkbf2(float a, float b) {
    __hip_bfloat162 h = __float22bfloat162_rn(make_float2(a, b));
    union { __hip_bfloat162 h; uint u; } cv;
    cv.h = h;
    return cv.u;
}

// async global->LDS: 16B/lane; LDS dest = wave-uniform base + lane*16
__device__ __forceinline__ void gld16(const void* g, void* l) {
    __builtin_amdgcn_global_load_lds((const __attribute__((address_space(1))) void*)g,
                                     (__attribute__((address_space(3))) void*)l,
                                     16, 0, 0);
}

// ---------------- fused fp32 -> bf16 conversion ----------------
__global__ __launch_bounds__(256) void to_bf16_3(const float* __restrict__ a, ushort* __restrict__ oa, int na,
                                                 const float* __restrict__ b, ushort* __restrict__ ob, int nb,
                                                 const float* __restrict__ c, ushort* __restrict__ oc, int nc) {
    int i = (blockIdx.x * 256 + threadIdx.x) * 4;
    const float* src;
    ushort* dst;
    if (i < na)                { src = a + i;            dst = oa + i; }
    else if (i < na + nb)      { src = b + (i - na);     dst = ob + (i - na); }
    else if (i < na + nb + nc) { src = c + (i - na - nb); dst = oc + (i - na - nb); }
    else return;
    float4 v = *(const float4*)src;
    uint2 u;
    u.x = pkbf2(v.x, v.y);
    u.y = pkbf2(v.z, v.w);
    *(uint2*)dst = u;
}

// ---------------- bf16 BT-GEMM, swizzled LDS, gld16 staging ----------------
// Tile: (MI*32) x 128, 4 waves, wave = (MI*16) x 64. BK=32.
// Swizzle (4 chunks of 16B per 64B row): chunk c of row r stored at slot
// (c + (r>>1)) & 3  -> b128 frag reads hit all 8 bank-groups, 2-way max (free).
// MODE 0: fp32 out row-major. MODE 1: qkv scatter, V transposed to [b,h,d,s].
template <int MODE, int MI>
__global__ __launch_bounds__(256) void gemm_bt(const ushort* __restrict__ A,
                                               const ushort* __restrict__ Bt,
                                               const float* __restrict__ bias,
                                               void* __restrict__ Cout,
                                               int M, int N, int K) {
    __shared__ ushort As[MI * 32 * 32];
    __shared__ ushort Bs[128 * 32];

    const int tid  = threadIdx.x;
    const int wave = tid >> 6;
    const int lane = tid & 63;
    const int ln16 = lane & 15;
    const int quad = lane >> 4;
    const int wm = wave >> 1, wn = wave & 1;
    const int bm = blockIdx.x * (MI * 32);
    const int bn = blockIdx.y * 128;

    ffrag acc[MI][4];
#pragma unroll
    for (int mi = 0; mi < MI; ++mi)
#pragma unroll
        for (int ni = 0; ni < 4; ++ni)
            acc[mi][ni] = (ffrag){0.f, 0.f, 0.f, 0.f};

    for (int k0 = 0; k0 < K; k0 += 32) {
#pragma unroll
        for (int p = 0; p < MI / 2; ++p) {
            int g0 = p * 256 + wave * 64;        // wave-uniform chunk base
            int g  = g0 + lane;
            int r  = g >> 2;
            int c  = ((g & 3) - (r >> 1)) & 3;   // inverse swizzle
            gld16(A + (size_t)(bm + r) * K + k0 + c * 8, (ushort*)As + g0 * 8);
        }
#pragma unroll
        for (int p = 0; p < 2; ++p) {
            int g0 = p * 256 + wave * 64;
            int g  = g0 + lane;
            int r  = g >> 2;
            int c  = ((g & 3) - (r >> 1)) & 3;
            gld16(Bt + (size_t)(bn + r) * K + k0 + c * 8, (ushort*)Bs + g0 * 8);
        }
        __syncthreads();

        bfrag af[MI], bf[4];
#pragma unroll
        for (int mi = 0; mi < MI; ++mi) {
            int r = wm * (MI * 16) + mi * 16 + ln16;
            af[mi] = *(const bfrag*)&As[r * 32 + ((quad + (r >> 1)) & 3) * 8];
        }
#pragma unroll
        for (int ni = 0; ni < 4; ++ni) {
            int r = wn * 64 + ni * 16 + ln16;
            bf[ni] = *(const bfrag*)&Bs[r * 32 + ((quad + (r >> 1)) & 3) * 8];
        }
#pragma unroll
        for (int mi = 0; mi < MI; ++mi)
#pragma unroll
            for (int ni = 0; ni < 4; ++ni)
                acc[mi][ni] = mfma16(af[mi], bf[ni], acc[mi][ni]);
        __syncthreads();
    }

#pragma unroll
    for (int mi = 0; mi < MI; ++mi) {
#pragma unroll
        for (int ni = 0; ni < 4; ++ni) {
#pragma unroll
            for (int reg = 0; reg < 4; ++reg) {
                int row = bm + wm * (MI * 16) + mi * 16 + quad * 4 + reg;
                int col = bn + wn * 64 + ni * 16 + ln16;
                float v = acc[mi][ni][reg] + bias[col];
                if (MODE == 0) {
                    ((float*)Cout)[(size_t)row * N + col] = v;
                } else {
                    int which = col >> 10;        // 0=q 1=k 2=v
                    int rem = col & 1023;
                    int h = rem >> 6;
                    int d = rem & 63;
                    int b = row >> 11;
                    int s = row & 2047;
                    if (which == 0) v *= 0.125f;  // 1/sqrt(64)
                    size_t dst;
                    if (which == 2) {
                        dst = 2ull * (BN * HN * SDIM * DDIM) +
                              (((size_t)(b * HN + h)) * DDIM + d) * SDIM + s;
                    } else {
                        dst = (size_t)which * (BN * HN * SDIM * DDIM) +
                              (((size_t)(b * HN + h)) * SDIM + s) * DDIM + d;
                    }
                    ((ushort*)Cout)[dst] = f2bf(v);
                }
            }
        }
    }
}

// ---------------- flash attention: 128q/block, dbuf K/V + async prefetch ----------------
// grid (S/128, B*H), 256 threads = 4 waves; wave handles 32 query rows
// (2 register Q-frag groups). Fixed-shift softmax (no running max).
// K/V tiles 64x64 bf16, swizzled (8 chunks/row): chunk c of row r at slot (c+r)&7.
__global__ __launch_bounds__(256) void flash_attn(const ushort* __restrict__ Qb,
                                                  const ushort* __restrict__ Kb,
                                                  const ushort* __restrict__ Vtb,
                                                  const float* __restrict__ decay_ptr,
                                                  ushort* __restrict__ Ob) {
    __shared__ ushort KVs[2][2][4096];   // [buf][K / Vt][64 rows x 8 chunks, swizzled]
    __shared__ ushort Pb[128][72];       // Q staging, then P exchange (per-wave rows)

    const int tid  = threadIdx.x;
    const int wave = tid >> 6;
    const int lane = tid & 63;
    const int ln16 = lane & 15;
    const int quad = lane >> 4;

    const int bh = blockIdx.y;
    const int q0 = blockIdx.x * 128;
    const size_t head_off = (size_t)bh * SDIM * DDIM;
    const float absa = fabsf(decay_ptr[0]);
    const float LOG2E = 1.442695041f;
    const float M0L2 = -17.3123404f;     // -12 * log2(e)

    auto stageKV = [&](int t0, int buf) {
#pragma unroll
        for (int p = 0; p < 2; ++p) {
            int g0 = p * 256 + wave * 64;   // wave-uniform
            int g  = g0 + lane;
            int r  = g >> 3;
            int c  = (g - r) & 7;           // inverse swizzle
            gld16(Kb  + head_off + (size_t)(t0 + r) * DDIM + c * 8,
                  (ushort*)&KVs[buf][0][0] + g0 * 8);
            gld16(Vtb + head_off + (size_t)r * SDIM + t0 + c * 8,
                  (ushort*)&KVs[buf][1][0] + g0 * 8);
        }
    };

    // stage Q (128x64) into Pb + K/V tile 0 into buf 0
#pragma unroll
    for (int p = 0; p < 4; ++p) {
        int idx = p * 256 + tid;
        int r = idx >> 3, c = (idx & 7) * 8;
        *(uint4*)&Pb[r][c] = *(const uint4*)(Qb + head_off + (size_t)(q0 + r) * DDIM + c);
    }
    stageKV(0, 0);
    __syncthreads();

    bfrag aq[2][2];
#pragma unroll
    for (int ng = 0; ng < 2; ++ng)
#pragma unroll
        for (int kb = 0; kb < 2; ++kb)
            aq[ng][kb] = *(const bfrag*)&Pb[wave * 32 + ng * 16 + ln16][kb * 32 + quad * 8];

    // decay factor tables (all <= 1)
    float Ec[4][4], Fc[4][4];
#pragma unroll
    for (int ni = 0; ni < 4; ++ni)
#pragma unroll
        for (int reg = 0; reg < 4; ++reg) {
            int c = ni * 16 + quad * 4 + reg;
            Ec[ni][reg] = __expf(-absa * (float)(63 - c));
            Fc[ni][reg] = __expf(-absa * (float)c);
        }
    const float Er = __expf(-absa * (float)ln16);
    const float Fr = __expf(-absa * (float)(15 - ln16));

    float l[2] = {0.f, 0.f};
    ffrag o[2][4];
#pragma unroll
    for (int ng = 0; ng < 2; ++ng)
#pragma unroll
        for (int ni = 0; ni < 4; ++ni)
            o[ng][ni] = (ffrag){0.f, 0.f, 0.f, 0.f};

    for (int it = 0; it < 32; ++it) {
        const int t0 = it * 64;
        const int buf = it & 1;
        if (it + 1 < 32) stageKV(t0 + 64, buf ^ 1);   // async prefetch, drained by barrier

        const ushort* Kt = &KVs[buf][0][0];
        const ushort* Vt = &KVs[buf][1][0];

        // S^T = K * Q^T, K-frags read once, shared across both q-groups
        ffrag sc[2][4];
#pragma unroll
        for (int ng = 0; ng < 2; ++ng)
#pragma unroll
            for (int ni = 0; ni < 4; ++ni)
                sc[ng][ni] = (ffrag){0.f, 0.f, 0.f, 0.f};
#pragma unroll
        for (int ni = 0; ni < 4; ++ni) {
            const int rk = ni * 16 + ln16;
#pragma unroll
            for (int kb = 0; kb < 2; ++kb) {
                bfrag kf = *(const bfrag*)&Kt[rk * 64 + ((kb * 4 + quad + rk) & 7) * 8];
#pragma unroll
                for (int ng = 0; ng < 2; ++ng)
                    sc[ng][ni] = mfma16(kf, aq[ng][kb], sc[ng][ni]);
            }
        }

        // decay * score, fixed-shift softmax, pack P (all wave-uniform branches)
#pragma unroll
        for (int ng = 0; ng < 2; ++ng) {
            const int ds = q0 + wave * 32 + ng * 16 - t0;  // strip row0 - tile col0
            const int m = wave * 32 + ng * 16 + ln16;
            float hh = 0.f;
            if (ds >= 64)       hh = __expf(-absa * (float)(ds - 63)) * Er * LOG2E;
            else if (ds <= -16) hh = __expf(-absa * (float)(-ds - 15)) * Fr * LOG2E;
            float ll = 0.f;
#pragma unroll
            for (int ni = 0; ni < 4; ++ni) {
                float f[4];
                if (ds >= 64) {
#pragma unroll
                    for (int reg = 0; reg < 4; ++reg) f[reg] = hh * Ec[ni][reg];
                } else if (ds <= -16) {
#pragma unroll
                    for (int reg = 0; reg < 4; ++reg) f[reg] = hh * Fc[ni][reg];
                } else {
#pragma unroll
                    for (int reg = 0; reg < 4; ++reg) {
                        int c = ni * 16 + quad * 4 + reg;
                        f[reg] = __expf(-absa * fabsf((float)(ds + ln16 - c))) * LOG2E;
                    }
                }
                float p0 = exp2f(fmaf(sc[ng][ni][0], f[0], M0L2));
                float p1 = exp2f(fmaf(sc[ng][ni][1], f[1], M0L2));
                float p2 = exp2f(fmaf(sc[ng][ni][2], f[2], M0L2));
                float p3 = exp2f(fmaf(sc[ng][ni][3], f[3], M0L2));
                ll += (p0 + p1) + (p2 + p3);
                uint2 pk;
                pk.x = pkbf2(p0, p1);
                pk.y = pkbf2(p2, p3);
                *(uint2*)&Pb[m][ni * 16 + quad * 4] = pk;  // own-wave rows: no barrier
            }
            l[ng] += ll;
        }

        // O^T = V^T * P^T
        bfrag ap[2][2];
#pragma unroll
        for (int ng = 0; ng < 2; ++ng)
#pragma unroll
            for (int kb = 0; kb < 2; ++kb)
                ap[ng][kb] = *(const bfrag*)&Pb[wave * 32 + ng * 16 + ln16][kb * 32 + quad * 8];
#pragma unroll
        for (int ni = 0; ni < 4; ++ni) {
            const int rv = ni * 16 + ln16;
#pragma unroll
            for (int kb = 0; kb < 2; ++kb) {
                bfrag vf = *(const bfrag*)&Vt[rv * 64 + ((kb * 4 + quad + rv) & 7) * 8];
#pragma unroll
                for (int ng = 0; ng < 2; ++ng)
                    o[ng][ni] = mfma16(vf, ap[ng][kb], o[ng][ni]);
            }
        }
        __syncthreads();   // all reads of buf done; prefetch (vmcnt) drained
    }

    // epilogue
    const int b = bh / HN, h = bh % HN;
#pragma unroll
    for (int ng = 0; ng < 2; ++ng) {
        float lt = l[ng];
        lt += __shfl_xor(lt, 16);
        lt += __shfl_xor(lt, 32);
        float inv = 1.f / lt;
        const int s = q0 + wave * 32 + ng * 16 + ln16;
        ushort* dst = Ob + ((size_t)(b * SDIM + s)) * EDIM + h * DDIM + quad * 4;
#pragma unroll
        for (int ni = 0; ni < 4; ++ni) {
            uint2 pk;
            pk.x = pkbf2(o[ng][ni][0] * inv, o[ng][ni][1] * inv);
            pk.y = pkbf2(o[ng][ni][2] * inv, o[ng][ni][3] * inv);
            *(uint2*)(dst + ni * 16) = pk;
        }
    }
}

extern "C" void kernel_launch(void* const* d_in, const int* in_sizes, int n_in,
                              void* d_out, int out_size, void* d_ws, size_t ws_size,
                              hipStream_t stream) {
    const float* x      = (const float*)d_in[0];
    const float* Wqkv_w = (const float*)d_in[1];
    const float* Wqkv_b = (const float*)d_in[2];
    const float* out_w  = (const float*)d_in[3];
    const float* out_b  = (const float*)d_in[4];
    const float* dd     = (const float*)d_in[5];

    char* ws = (char*)d_ws;
    const size_t MB = 1024 * 1024;
    ushort* xb    = (ushort*)(ws + 0 * MB);
    ushort* wqkvb = (ushort*)(ws + 8 * MB);
    ushort* owb   = (ushort*)(ws + 14 * MB);
    ushort* qkvb  = (ushort*)(ws + 16 * MB);   // q,k:[b,h,s,d] v:[b,h,d,s]
    ushort* ob    = (ushort*)(ws + 40 * MB);

    const int n_x = BN * SDIM * EDIM;
    const int n_w = 3 * EDIM * EDIM;
    const int n_o = EDIM * EDIM;
    const int HSD = BN * HN * SDIM * DDIM;

    to_bf16_3<<<(n_x + n_w + n_o) / 1024, 256, 0, stream>>>(
        x, xb, n_x, Wqkv_w, wqkvb, n_w, out_w, owb, n_o);

    gemm_bt<1, 4><<<dim3(32, 24), 256, 0, stream>>>(xb, wqkvb, Wqkv_b, (void*)qkvb,
                                                    BN * SDIM, 3 * EDIM, EDIM);

    flash_attn<<<dim3(SDIM / 128, BN * HN), 256, 0, stream>>>(
        qkvb, qkvb + HSD, qkvb + 2 * HSD, dd, ob);

    gemm_bt<0, 2><<<dim3(64, 8), 256, 0, stream>>>(ob, owb, out_b, d_out,
                                                   BN * SDIM, EDIM, EDIM);
}

// Round 5
// 215.514 us; speedup vs baseline: 1.5334x; 1.1078x over previous
//
#include <hip/hip_runtime.h>
#include <hip/hip_bf16.h>

#define BN 2
#define SDIM 2048
#define EDIM 1024
#define HN 16
#define DDIM 64

typedef __attribute__((ext_vector_type(8))) short bfrag;
typedef __attribute__((ext_vector_type(4))) float ffrag;

__device__ __forceinline__ ffrag mfma16(bfrag a, bfrag b, ffrag c) {
    return __builtin_amdgcn_mfma_f32_16x16x32_bf16(a, b, c, 0, 0, 0);
}

__device__ __forceinline__ ushort f2bf(float f) {
    union { float f; unsigned u; } un;
    un.f = f;
    unsigned u = un.u;
    u += 0x7fffu + ((u >> 16) & 1u);   // RNE
    return (ushort)(u >> 16);
}

__device__ __forceinline__ uint pkbf2(float a, float b) {
    __hip_bfloat162 h = __float22bfloat162_rn(make_float2(a, b));
    union { __hip_bfloat162 h; uint u; } cv;
    cv.h = h;
    return cv.u;
}

// async global->LDS: 16B/lane; LDS dest = wave-uniform base + lane*16
__device__ __forceinline__ void gld16(const void* g, void* l) {
    __builtin_amdgcn_global_load_lds((const __attribute__((address_space(1))) void*)g,
                                     (__attribute__((address_space(3))) void*)l,
                                     16, 0, 0);
}

// ---------------- fused fp32 -> bf16 conversion ----------------
__global__ __launch_bounds__(256) void to_bf16_3(const float* __restrict__ a, ushort* __restrict__ oa, int na,
                                                 const float* __restrict__ b, ushort* __restrict__ ob, int nb,
                                                 const float* __restrict__ c, ushort* __restrict__ oc, int nc) {
    int i = (blockIdx.x * 256 + threadIdx.x) * 4;
    const float* src;
    ushort* dst;
    if (i < na)                { src = a + i;            dst = oa + i; }
    else if (i < na + nb)      { src = b + (i - na);     dst = ob + (i - na); }
    else if (i < na + nb + nc) { src = c + (i - na - nb); dst = oc + (i - na - nb); }
    else return;
    float4 v = *(const float4*)src;
    uint2 u;
    u.x = pkbf2(v.x, v.y);
    u.y = pkbf2(v.z, v.w);
    *(uint2*)dst = u;
}

// ---------------- bf16 BT-GEMM, swizzled LDS, gld16 staging ----------------
// Tile: (MI*32) x 128, 4 waves of 64. BK=32. Swizzle: 16B chunk c of row r
// stored at slot (c + (r>>1)) & 3.
// MODE 0: fp32 out row-major. MODE 1: qkv scatter, V transposed to [b,h,d,s]
// with V stores packed 4-wide along s (consecutive regs = consecutive s).
template <int MODE, int MI>
__global__ __launch_bounds__(256) void gemm_bt(const ushort* __restrict__ A,
                                               const ushort* __restrict__ Bt,
                                               const float* __restrict__ bias,
                                               void* __restrict__ Cout,
                                               int M, int N, int K) {
    __shared__ ushort As[MI * 32 * 32];
    __shared__ ushort Bs[128 * 32];

    const int tid  = threadIdx.x;
    const int wave = tid >> 6;
    const int lane = tid & 63;
    const int ln16 = lane & 15;
    const int quad = lane >> 4;
    const int wm = wave >> 1, wn = wave & 1;
    const int bm = blockIdx.x * (MI * 32);
    const int bn = blockIdx.y * 128;

    ffrag acc[MI][4];
#pragma unroll
    for (int mi = 0; mi < MI; ++mi)
#pragma unroll
        for (int ni = 0; ni < 4; ++ni)
            acc[mi][ni] = (ffrag){0.f, 0.f, 0.f, 0.f};

    for (int k0 = 0; k0 < K; k0 += 32) {
#pragma unroll
        for (int p = 0; p < MI / 2; ++p) {
            int g0 = p * 256 + wave * 64;        // wave-uniform chunk base
            int g  = g0 + lane;
            int r  = g >> 2;
            int c  = ((g & 3) - (r >> 1)) & 3;   // inverse swizzle
            gld16(A + (size_t)(bm + r) * K + k0 + c * 8, (ushort*)As + g0 * 8);
        }
#pragma unroll
        for (int p = 0; p < 2; ++p) {
            int g0 = p * 256 + wave * 64;
            int g  = g0 + lane;
            int r  = g >> 2;
            int c  = ((g & 3) - (r >> 1)) & 3;
            gld16(Bt + (size_t)(bn + r) * K + k0 + c * 8, (ushort*)Bs + g0 * 8);
        }
        __syncthreads();

        bfrag af[MI], bf[4];
#pragma unroll
        for (int mi = 0; mi < MI; ++mi) {
            int r = wm * (MI * 16) + mi * 16 + ln16;
            af[mi] = *(const bfrag*)&As[r * 32 + ((quad + (r >> 1)) & 3) * 8];
        }
#pragma unroll
        for (int ni = 0; ni < 4; ++ni) {
            int r = wn * 64 + ni * 16 + ln16;
            bf[ni] = *(const bfrag*)&Bs[r * 32 + ((quad + (r >> 1)) & 3) * 8];
        }
#pragma unroll
        for (int mi = 0; mi < MI; ++mi)
#pragma unroll
            for (int ni = 0; ni < 4; ++ni)
                acc[mi][ni] = mfma16(af[mi], bf[ni], acc[mi][ni]);
        __syncthreads();
    }

#pragma unroll
    for (int mi = 0; mi < MI; ++mi) {
#pragma unroll
        for (int ni = 0; ni < 4; ++ni) {
            int col = bn + wn * 64 + ni * 16 + ln16;
            float bc = bias[col];
            int row0 = bm + wm * (MI * 16) + mi * 16 + quad * 4;
            if (MODE == 0) {
#pragma unroll
                for (int reg = 0; reg < 4; ++reg)
                    ((float*)Cout)[(size_t)(row0 + reg) * N + col] = acc[mi][ni][reg] + bc;
            } else {
                int which = col >> 10;        // wave-uniform: 0=q 1=k 2=v
                int rem = col & 1023;
                int h = rem >> 6;
                int d = rem & 63;
                int b = row0 >> 11;
                int s0 = row0 & 2047;
                if (which == 2) {
                    // V transposed [b,h,d,s]: 4 regs = 4 consecutive s -> 8B store
                    float v0 = acc[mi][ni][0] + bc, v1 = acc[mi][ni][1] + bc;
                    float v2 = acc[mi][ni][2] + bc, v3 = acc[mi][ni][3] + bc;
                    uint2 pk;
                    pk.x = pkbf2(v0, v1);
                    pk.y = pkbf2(v2, v3);
                    size_t dst = 2ull * (BN * HN * SDIM * DDIM) +
                                 (((size_t)(b * HN + h)) * DDIM + d) * SDIM + s0;
                    *(uint2*)((ushort*)Cout + dst) = pk;
                } else {
                    float sc = (which == 0) ? 0.125f : 1.f;
#pragma unroll
                    for (int reg = 0; reg < 4; ++reg) {
                        float v = (acc[mi][ni][reg] + bc) * sc;
                        size_t dst = (size_t)which * (BN * HN * SDIM * DDIM) +
                                     (((size_t)(b * HN + h)) * SDIM + s0 + reg) * DDIM + d;
                        ((ushort*)Cout)[dst] = f2bf(v);
                    }
                }
            }
        }
    }
}

// ---------------- flash attention: 8 waves, 16 q/wave, dbuf K/V prefetch ----------------
// grid (S/128, B*H), 512 threads = 8 waves; wave owns 16 query rows.
// Fixed-shift softmax; l summed via MFMA with ones; K/V tiles swizzled.
__global__ __launch_bounds__(512, 4) void flash_attn(const ushort* __restrict__ Qb,
                                                     const ushort* __restrict__ Kb,
                                                     const ushort* __restrict__ Vtb,
                                                     const float* __restrict__ decay_ptr,
                                                     ushort* __restrict__ Ob) {
    __shared__ ushort KVs[2][2][4096];   // [buf][K / Vt][64 rows x 8 chunks, swizzled]
    __shared__ ushort Pb[128][72];       // Q staging, then P exchange (per-wave rows)

    const int tid  = threadIdx.x;
    const int wave = tid >> 6;
    const int lane = tid & 63;
    const int ln16 = lane & 15;
    const int quad = lane >> 4;

    const int bh = blockIdx.y;
    const int q0 = blockIdx.x * 128;
    const size_t head_off = (size_t)bh * SDIM * DDIM;
    const float absa = fabsf(decay_ptr[0]);
    const float LOG2E = 1.442695041f;
    const float M0L2 = -17.3123404f;     // -12 * log2(e)

    auto stageKV = [&](int t0, int buf) {
        int g0 = wave * 64;              // wave-uniform; 512 lanes cover 512 chunks
        int g  = g0 + lane;
        int r  = g >> 3;
        int c  = (g - r) & 7;            // inverse swizzle
        gld16(Kb  + head_off + (size_t)(t0 + r) * DDIM + c * 8,
              (ushort*)&KVs[buf][0][0] + g0 * 8);
        gld16(Vtb + head_off + (size_t)r * SDIM + t0 + c * 8,
              (ushort*)&KVs[buf][1][0] + g0 * 8);
    };

    // stage Q (128x64) into Pb + K/V tile 0 into buf 0
#pragma unroll
    for (int p = 0; p < 2; ++p) {
        int idx = p * 512 + tid;
        int r = idx >> 3, c = (idx & 7) * 8;
        *(uint4*)&Pb[r][c] = *(const uint4*)(Qb + head_off + (size_t)(q0 + r) * DDIM + c);
    }
    stageKV(0, 0);
    __syncthreads();

    bfrag aq[2];
#pragma unroll
    for (int kb = 0; kb < 2; ++kb)
        aq[kb] = *(const bfrag*)&Pb[wave * 16 + ln16][kb * 32 + quad * 8];

    bfrag ones;
#pragma unroll
    for (int i = 0; i < 8; ++i) ones[i] = (short)0x3F80;   // bf16 1.0

    // factored decay tables: Ec[c]=e^{-a(63-c)} = Epw[ni]*EcB[reg], Fc[c]=e^{-a c}=Fpw[ni]*FcB[reg]
    float EcB[4], FcB[4], Epw[4], Fpw[4];
#pragma unroll
    for (int reg = 0; reg < 4; ++reg) {
        int cr = quad * 4 + reg;
        EcB[reg] = __expf(-absa * (float)(15 - cr));
        FcB[reg] = __expf(-absa * (float)cr);
    }
#pragma unroll
    for (int ni = 0; ni < 4; ++ni) {
        Epw[ni] = __expf(-absa * (float)(16 * (3 - ni)));
        Fpw[ni] = __expf(-absa * (float)(16 * ni));
    }
    const float Er = __expf(-absa * (float)ln16);
    const float Fr = __expf(-absa * (float)(15 - ln16));

    ffrag lacc = (ffrag){0.f, 0.f, 0.f, 0.f};
    ffrag o[4];
#pragma unroll
    for (int ni = 0; ni < 4; ++ni) o[ni] = (ffrag){0.f, 0.f, 0.f, 0.f};

    const int m = wave * 16 + ln16;      // this lane's query row (block-local)

    for (int it = 0; it < 32; ++it) {
        const int t0 = it * 64;
        const int buf = it & 1;
        if (it + 1 < 32) stageKV(t0 + 64, buf ^ 1);   // async prefetch

        const ushort* Kt = &KVs[buf][0][0];
        const ushort* Vt = &KVs[buf][1][0];

        // S^T = K * Q^T : sc[ni][reg] = S[m][t = t0 + ni*16 + quad*4 + reg]
        ffrag sc[4];
#pragma unroll
        for (int ni = 0; ni < 4; ++ni) {
            ffrag a = (ffrag){0.f, 0.f, 0.f, 0.f};
            const int rk = ni * 16 + ln16;
#pragma unroll
            for (int kb = 0; kb < 2; ++kb) {
                bfrag kf = *(const bfrag*)&Kt[rk * 64 + ((kb * 4 + quad + rk) & 7) * 8];
                a = mfma16(kf, aq[kb], a);
            }
            sc[ni] = a;
        }

        // decay * score -> p = exp2(fma(s, f, M0L2)); pack P to own-wave LDS rows
        const int ds = q0 + wave * 16 - t0;   // strip row0 - tile col0 (mult of 16)
        float hh = 0.f;
        if (ds >= 64)       hh = __expf(-absa * (float)(ds - 63)) * Er * LOG2E;
        else if (ds <= -16) hh = __expf(-absa * (float)(-ds - 15)) * Fr * LOG2E;

#pragma unroll
        for (int ni = 0; ni < 4; ++ni) {
            float f0, f1, f2, f3;
            if (ds >= 64) {
                float hn = hh * Epw[ni];
                f0 = hn * EcB[0]; f1 = hn * EcB[1]; f2 = hn * EcB[2]; f3 = hn * EcB[3];
            } else if (ds <= -16) {
                float hn = hh * Fpw[ni];
                f0 = hn * FcB[0]; f1 = hn * FcB[1]; f2 = hn * FcB[2]; f3 = hn * FcB[3];
            } else {
                // diagonal band: per-element (4 of 32 tiles per wave)
                int c0 = ni * 16 + quad * 4;
                f0 = __expf(-absa * fabsf((float)(ds + ln16 - c0)))     * LOG2E;
                f1 = __expf(-absa * fabsf((float)(ds + ln16 - c0 - 1))) * LOG2E;
                f2 = __expf(-absa * fabsf((float)(ds + ln16 - c0 - 2))) * LOG2E;
                f3 = __expf(-absa * fabsf((float)(ds + ln16 - c0 - 3))) * LOG2E;
            }
            float p0 = exp2f(fmaf(sc[ni][0], f0, M0L2));
            float p1 = exp2f(fmaf(sc[ni][1], f1, M0L2));
            float p2 = exp2f(fmaf(sc[ni][2], f2, M0L2));
            float p3 = exp2f(fmaf(sc[ni][3], f3, M0L2));
            uint2 pk;
            pk.x = pkbf2(p0, p1);
            pk.y = pkbf2(p2, p3);
            *(uint2*)&Pb[m][ni * 16 + quad * 4] = pk;   // own-wave rows: no barrier
        }

        bfrag ap[2];
#pragma unroll
        for (int kb = 0; kb < 2; ++kb)
            ap[kb] = *(const bfrag*)&Pb[m][kb * 32 + quad * 8];

        // l += ones * P^T (full k=32 sum -> every lane of column gets row-total)
        // O^T = V^T * P^T
#pragma unroll
        for (int kb = 0; kb < 2; ++kb)
            lacc = mfma16(ones, ap[kb], lacc);
#pragma unroll
        for (int ni = 0; ni < 4; ++ni) {
            const int rv = ni * 16 + ln16;
#pragma unroll
            for (int kb = 0; kb < 2; ++kb) {
                bfrag vf = *(const bfrag*)&Vt[rv * 64 + ((kb * 4 + quad + rv) & 7) * 8];
                o[ni] = mfma16(vf, ap[kb], o[ni]);
            }
        }
        __syncthreads();   // all reads of buf done; prefetch vmcnt drained
    }

    // epilogue: every lane has full l for its query in lacc[0]
    const float inv = 1.f / lacc[0];
    const int b = bh / HN, h = bh % HN;
    const int s = q0 + m;
    ushort* dst = Ob + ((size_t)(b * SDIM + s)) * EDIM + h * DDIM + quad * 4;
#pragma unroll
    for (int ni = 0; ni < 4; ++ni) {
        uint2 pk;
        pk.x = pkbf2(o[ni][0] * inv, o[ni][1] * inv);
        pk.y = pkbf2(o[ni][2] * inv, o[ni][3] * inv);
        *(uint2*)(dst + ni * 16) = pk;
    }
}

extern "C" void kernel_launch(void* const* d_in, const int* in_sizes, int n_in,
                              void* d_out, int out_size, void* d_ws, size_t ws_size,
                              hipStream_t stream) {
    const float* x      = (const float*)d_in[0];
    const float* Wqkv_w = (const float*)d_in[1];
    const float* Wqkv_b = (const float*)d_in[2];
    const float* out_w  = (const float*)d_in[3];
    const float* out_b  = (const float*)d_in[4];
    const float* dd     = (const float*)d_in[5];

    char* ws = (char*)d_ws;
    const size_t MB = 1024 * 1024;
    ushort* xb    = (ushort*)(ws + 0 * MB);
    ushort* wqkvb = (ushort*)(ws + 8 * MB);
    ushort* owb   = (ushort*)(ws + 14 * MB);
    ushort* qkvb  = (ushort*)(ws + 16 * MB);   // q,k:[b,h,s,d] v:[b,h,d,s]
    ushort* ob    = (ushort*)(ws + 40 * MB);

    const int n_x = BN * SDIM * EDIM;
    const int n_w = 3 * EDIM * EDIM;
    const int n_o = EDIM * EDIM;
    const int HSD = BN * HN * SDIM * DDIM;

    to_bf16_3<<<(n_x + n_w + n_o) / 1024, 256, 0, stream>>>(
        x, xb, n_x, Wqkv_w, wqkvb, n_w, out_w, owb, n_o);

    gemm_bt<1, 4><<<dim3(32, 24), 256, 0, stream>>>(xb, wqkvb, Wqkv_b, (void*)qkvb,
                                                    BN * SDIM, 3 * EDIM, EDIM);

    flash_attn<<<dim3(SDIM / 128, BN * HN), 512, 0, stream>>>(
        qkvb, qkvb + HSD, qkvb + 2 * HSD, dd, ob);

    gemm_bt<0, 2><<<dim3(64, 8), 256, 0, stream>>>(ob, owb, out_b, d_out,
                                                   BN * SDIM, EDIM, EDIM);
}

// Round 6
// 196.601 us; speedup vs baseline: 1.6810x; 1.0962x over previous
//
#include <hip/hip_runtime.h>
#include <hip/hip_bf16.h>

#define BN 2
#define SDIM 2048
#define EDIM 1024
#define HN 16
#define DDIM 64

typedef __attribute__((ext_vector_type(8))) short bfrag;
typedef __attribute__((ext_vector_type(4))) float ffrag;

__device__ __forceinline__ ffrag mfma16(bfrag a, bfrag b, ffrag c) {
    return __builtin_amdgcn_mfma_f32_16x16x32_bf16(a, b, c, 0, 0, 0);
}

__device__ __forceinline__ ushort f2bf(float f) {
    union { float f; unsigned u; } un;
    un.f = f;
    unsigned u = un.u;
    u += 0x7fffu + ((u >> 16) & 1u);   // RNE
    return (ushort)(u >> 16);
}

__device__ __forceinline__ uint pkbf2(float a, float b) {
    __hip_bfloat162 h = __float22bfloat162_rn(make_float2(a, b));
    union { __hip_bfloat162 h; uint u; } cv;
    cv.h = h;
    return cv.u;
}

// async global->LDS: 16B/lane; LDS dest = wave-uniform base + lane*16
__device__ __forceinline__ void gld16(const void* g, void* l) {
    __builtin_amdgcn_global_load_lds((const __attribute__((address_space(1))) void*)g,
                                     (__attribute__((address_space(3))) void*)l,
                                     16, 0, 0);
}

// ---------------- fused fp32 -> bf16 conversion ----------------
__global__ __launch_bounds__(256) void to_bf16_3(const float* __restrict__ a, ushort* __restrict__ oa, int na,
                                                 const float* __restrict__ b, ushort* __restrict__ ob, int nb,
                                                 const float* __restrict__ c, ushort* __restrict__ oc, int nc) {
    int i = (blockIdx.x * 256 + threadIdx.x) * 4;
    const float* src;
    ushort* dst;
    if (i < na)                { src = a + i;            dst = oa + i; }
    else if (i < na + nb)      { src = b + (i - na);     dst = ob + (i - na); }
    else if (i < na + nb + nc) { src = c + (i - na - nb); dst = oc + (i - na - nb); }
    else return;
    float4 v = *(const float4*)src;
    uint2 u;
    u.x = pkbf2(v.x, v.y);
    u.y = pkbf2(v.z, v.w);
    *(uint2*)dst = u;
}

// ---------------- bf16 BT-GEMM, swizzled LDS, gld16 staging ----------------
template <int MODE, int MI>
__global__ __launch_bounds__(256) void gemm_bt(const ushort* __restrict__ A,
                                               const ushort* __restrict__ Bt,
                                               const float* __restrict__ bias,
                                               void* __restrict__ Cout,
                                               int M, int N, int K) {
    __shared__ ushort As[MI * 32 * 32];
    __shared__ ushort Bs[128 * 32];

    const int tid  = threadIdx.x;
    const int wave = tid >> 6;
    const int lane = tid & 63;
    const int ln16 = lane & 15;
    const int quad = lane >> 4;
    const int wm = wave >> 1, wn = wave & 1;
    const int bm = blockIdx.x * (MI * 32);
    const int bn = blockIdx.y * 128;

    ffrag acc[MI][4];
#pragma unroll
    for (int mi = 0; mi < MI; ++mi)
#pragma unroll
        for (int ni = 0; ni < 4; ++ni)
            acc[mi][ni] = (ffrag){0.f, 0.f, 0.f, 0.f};

    for (int k0 = 0; k0 < K; k0 += 32) {
#pragma unroll
        for (int p = 0; p < MI / 2; ++p) {
            int g0 = p * 256 + wave * 64;
            int g  = g0 + lane;
            int r  = g >> 2;
            int c  = ((g & 3) - (r >> 1)) & 3;   // inverse swizzle
            gld16(A + (size_t)(bm + r) * K + k0 + c * 8, (ushort*)As + g0 * 8);
        }
#pragma unroll
        for (int p = 0; p < 2; ++p) {
            int g0 = p * 256 + wave * 64;
            int g  = g0 + lane;
            int r  = g >> 2;
            int c  = ((g & 3) - (r >> 1)) & 3;
            gld16(Bt + (size_t)(bn + r) * K + k0 + c * 8, (ushort*)Bs + g0 * 8);
        }
        __syncthreads();

        bfrag af[MI], bf[4];
#pragma unroll
        for (int mi = 0; mi < MI; ++mi) {
            int r = wm * (MI * 16) + mi * 16 + ln16;
            af[mi] = *(const bfrag*)&As[r * 32 + ((quad + (r >> 1)) & 3) * 8];
        }
#pragma unroll
        for (int ni = 0; ni < 4; ++ni) {
            int r = wn * 64 + ni * 16 + ln16;
            bf[ni] = *(const bfrag*)&Bs[r * 32 + ((quad + (r >> 1)) & 3) * 8];
        }
#pragma unroll
        for (int mi = 0; mi < MI; ++mi)
#pragma unroll
            for (int ni = 0; ni < 4; ++ni)
                acc[mi][ni] = mfma16(af[mi], bf[ni], acc[mi][ni]);
        __syncthreads();
    }

#pragma unroll
    for (int mi = 0; mi < MI; ++mi) {
#pragma unroll
        for (int ni = 0; ni < 4; ++ni) {
            int col = bn + wn * 64 + ni * 16 + ln16;
            float bc = bias[col];
            int row0 = bm + wm * (MI * 16) + mi * 16 + quad * 4;
            if (MODE == 0) {
#pragma unroll
                for (int reg = 0; reg < 4; ++reg)
                    ((float*)Cout)[(size_t)(row0 + reg) * N + col] = acc[mi][ni][reg] + bc;
            } else {
                int which = col >> 10;        // wave-uniform: 0=q 1=k 2=v
                int rem = col & 1023;
                int h = rem >> 6;
                int d = rem & 63;
                int b = row0 >> 11;
                int s0 = row0 & 2047;
                if (which == 2) {
                    float v0 = acc[mi][ni][0] + bc, v1 = acc[mi][ni][1] + bc;
                    float v2 = acc[mi][ni][2] + bc, v3 = acc[mi][ni][3] + bc;
                    uint2 pk;
                    pk.x = pkbf2(v0, v1);
                    pk.y = pkbf2(v2, v3);
                    size_t dst = 2ull * (BN * HN * SDIM * DDIM) +
                                 (((size_t)(b * HN + h)) * DDIM + d) * SDIM + s0;
                    *(uint2*)((ushort*)Cout + dst) = pk;
                } else {
                    float sc = (which == 0) ? 0.125f : 1.f;
#pragma unroll
                    for (int reg = 0; reg < 4; ++reg) {
                        float v = (acc[mi][ni][reg] + bc) * sc;
                        size_t dst = (size_t)which * (BN * HN * SDIM * DDIM) +
                                     (((size_t)(b * HN + h)) * SDIM + s0 + reg) * DDIM + d;
                        ((ushort*)Cout)[dst] = f2bf(v);
                    }
                }
            }
        }
    }
}

// ---------------- per-head V tile-sums + prefix ----------------
// grid 32 (= B*H), 64 threads (= d). PS[bh][k][d] = sum of V[t][d] for tiles < k,
// k in [0,32]. Vtb layout [b,h,d,s].
__global__ __launch_bounds__(64) void vsum_prefix(const ushort* __restrict__ Vtb,
                                                  float* __restrict__ PS) {
    const int bh = blockIdx.x;
    const int d  = threadIdx.x;
    const ushort* row = Vtb + ((size_t)bh * DDIM + d) * SDIM;
    float* ps = PS + (size_t)bh * 33 * 64;
    float run = 0.f;
    for (int k = 0; k < 32; ++k) {
        ps[k * 64 + d] = run;
        float s = 0.f;
#pragma unroll
        for (int j = 0; j < 64; j += 8) {
            uint4 v = *(const uint4*)(row + k * 64 + j);
            ushort tmp[8];
            *(uint4*)tmp = v;
#pragma unroll
            for (int e = 0; e < 8; ++e) {
                union { float f; uint u; } c;
                c.u = ((uint)tmp[e]) << 16;
                s += c.f;
            }
        }
        run += s;
    }
    ps[32 * 64 + d] = run;
}

// ---------------- flash attention with near-band + closed-form far field ----------------
// p = exp(s*e^{-a*dist} - 12). For a*dist >= 16, p == e^{-12} to ~1e-11 abs, so
// far tiles contribute e^{-12}*sum(V) (from PS prefix sums) and 64*e^{-12} to l.
// Near band [tlo,thi] computed exactly (identical math to full loop).
__global__ __launch_bounds__(512, 4) void flash_attn(const ushort* __restrict__ Qb,
                                                     const ushort* __restrict__ Kb,
                                                     const ushort* __restrict__ Vtb,
                                                     const float* __restrict__ decay_ptr,
                                                     const float* __restrict__ PS,
                                                     ushort* __restrict__ Ob) {
    __shared__ ushort KVs[2][2][4096];   // [buf][K / Vt][64 rows x 8 chunks, swizzled]
    __shared__ ushort Pb[128][72];       // Q staging, then P exchange (per-wave rows)
    __shared__ float  Fv[64];            // far-field V sum per d

    const int tid  = threadIdx.x;
    const int wave = tid >> 6;
    const int lane = tid & 63;
    const int ln16 = lane & 15;
    const int quad = lane >> 4;

    const int bh = blockIdx.y;
    const int q0 = blockIdx.x * 128;
    const size_t head_off = (size_t)bh * SDIM * DDIM;
    const float absa = fabsf(decay_ptr[0]);
    const float LOG2E = 1.442695041f;
    const float M0L2 = -17.3123404f;     // -12 * log2(e)
    const float E12 = 6.144212353e-6f;   // e^-12

    // near band: tiles with a*min-dist(block q-range, tile) < 16
    int Dstar = (absa > 1e-5f) ? (int)ceilf(16.0f / absa) : (4 * SDIM);
    int lo = q0 - 63 - Dstar; if (lo < 0) lo = 0;
    int hi = q0 + 127 + Dstar; if (hi > SDIM - 1) hi = SDIM - 1;
    const int tlo = lo >> 6;
    const int thi = hi >> 6;
    const int ntiles = thi - tlo + 1;

    // far-field V sums: Fv[d] = PS[tlo] + PS[32] - PS[thi+1]
    if (tid < 64) {
        const float* ps = PS + (size_t)bh * 33 * 64;
        Fv[tid] = ps[tlo * 64 + tid] + ps[32 * 64 + tid] - ps[(thi + 1) * 64 + tid];
    }

    auto stageKV = [&](int t0, int buf) {
        int g0 = wave * 64;
        int g  = g0 + lane;
        int r  = g >> 3;
        int c  = (g - r) & 7;            // inverse swizzle
        gld16(Kb  + head_off + (size_t)(t0 + r) * DDIM + c * 8,
              (ushort*)&KVs[buf][0][0] + g0 * 8);
        gld16(Vtb + head_off + (size_t)r * SDIM + t0 + c * 8,
              (ushort*)&KVs[buf][1][0] + g0 * 8);
    };

    // stage Q (128x64) into Pb + first K/V tile into buf 0
#pragma unroll
    for (int p = 0; p < 2; ++p) {
        int idx = p * 512 + tid;
        int r = idx >> 3, c = (idx & 7) * 8;
        *(uint4*)&Pb[r][c] = *(const uint4*)(Qb + head_off + (size_t)(q0 + r) * DDIM + c);
    }
    stageKV(tlo * 64, 0);
    __syncthreads();

    bfrag aq[2];
#pragma unroll
    for (int kb = 0; kb < 2; ++kb)
        aq[kb] = *(const bfrag*)&Pb[wave * 16 + ln16][kb * 32 + quad * 8];

    bfrag ones;
#pragma unroll
    for (int i = 0; i < 8; ++i) ones[i] = (short)0x3F80;   // bf16 1.0

    float EcB[4], FcB[4], Epw[4], Fpw[4];
#pragma unroll
    for (int reg = 0; reg < 4; ++reg) {
        int cr = quad * 4 + reg;
        EcB[reg] = __expf(-absa * (float)(15 - cr));
        FcB[reg] = __expf(-absa * (float)cr);
    }
#pragma unroll
    for (int ni = 0; ni < 4; ++ni) {
        Epw[ni] = __expf(-absa * (float)(16 * (3 - ni)));
        Fpw[ni] = __expf(-absa * (float)(16 * ni));
    }
    const float Er = __expf(-absa * (float)ln16);
    const float Fr = __expf(-absa * (float)(15 - ln16));

    ffrag lacc = (ffrag){0.f, 0.f, 0.f, 0.f};
    ffrag o[4];
#pragma unroll
    for (int ni = 0; ni < 4; ++ni) o[ni] = (ffrag){0.f, 0.f, 0.f, 0.f};

    const int m = wave * 16 + ln16;

    for (int it = 0; it < ntiles; ++it) {
        const int t0 = (tlo + it) * 64;
        const int buf = it & 1;
        if (it + 1 < ntiles) stageKV(t0 + 64, buf ^ 1);   // async prefetch

        const ushort* Kt = &KVs[buf][0][0];
        const ushort* Vt = &KVs[buf][1][0];

        // S^T = K * Q^T
        ffrag sc[4];
#pragma unroll
        for (int ni = 0; ni < 4; ++ni) {
            ffrag a = (ffrag){0.f, 0.f, 0.f, 0.f};
            const int rk = ni * 16 + ln16;
#pragma unroll
            for (int kb = 0; kb < 2; ++kb) {
                bfrag kf = *(const bfrag*)&Kt[rk * 64 + ((kb * 4 + quad + rk) & 7) * 8];
                a = mfma16(kf, aq[kb], a);
            }
            sc[ni] = a;
        }

        // p = exp2(fma(s, decay*log2e, -12*log2e)); pack P to own-wave LDS rows
        const int ds = q0 + wave * 16 - t0;
        float hh = 0.f;
        if (ds >= 64)       hh = __expf(-absa * (float)(ds - 63)) * Er * LOG2E;
        else if (ds <= -16) hh = __expf(-absa * (float)(-ds - 15)) * Fr * LOG2E;

#pragma unroll
        for (int ni = 0; ni < 4; ++ni) {
            float f0, f1, f2, f3;
            if (ds >= 64) {
                float hn = hh * Epw[ni];
                f0 = hn * EcB[0]; f1 = hn * EcB[1]; f2 = hn * EcB[2]; f3 = hn * EcB[3];
            } else if (ds <= -16) {
                float hn = hh * Fpw[ni];
                f0 = hn * FcB[0]; f1 = hn * FcB[1]; f2 = hn * FcB[2]; f3 = hn * FcB[3];
            } else {
                int c0 = ni * 16 + quad * 4;
                f0 = __expf(-absa * fabsf((float)(ds + ln16 - c0)))     * LOG2E;
                f1 = __expf(-absa * fabsf((float)(ds + ln16 - c0 - 1))) * LOG2E;
                f2 = __expf(-absa * fabsf((float)(ds + ln16 - c0 - 2))) * LOG2E;
                f3 = __expf(-absa * fabsf((float)(ds + ln16 - c0 - 3))) * LOG2E;
            }
            float p0 = exp2f(fmaf(sc[ni][0], f0, M0L2));
            float p1 = exp2f(fmaf(sc[ni][1], f1, M0L2));
            float p2 = exp2f(fmaf(sc[ni][2], f2, M0L2));
            float p3 = exp2f(fmaf(sc[ni][3], f3, M0L2));
            uint2 pk;
            pk.x = pkbf2(p0, p1);
            pk.y = pkbf2(p2, p3);
            *(uint2*)&Pb[m][ni * 16 + quad * 4] = pk;   // own-wave rows: no barrier
        }

        bfrag ap[2];
#pragma unroll
        for (int kb = 0; kb < 2; ++kb)
            ap[kb] = *(const bfrag*)&Pb[m][kb * 32 + quad * 8];

#pragma unroll
        for (int kb = 0; kb < 2; ++kb)
            lacc = mfma16(ones, ap[kb], lacc);
#pragma unroll
        for (int ni = 0; ni < 4; ++ni) {
            const int rv = ni * 16 + ln16;
#pragma unroll
            for (int kb = 0; kb < 2; ++kb) {
                bfrag vf = *(const bfrag*)&Vt[rv * 64 + ((kb * 4 + quad + rv) & 7) * 8];
                o[ni] = mfma16(vf, ap[kb], o[ni]);
            }
        }
        __syncthreads();
    }

    // epilogue: add far field, normalize, store
    const float farl = E12 * (float)(SDIM - 64 * ntiles);
    const float inv = 1.f / (lacc[0] + farl);
    const int b = bh / HN, h = bh % HN;
    const int s = q0 + m;
    ushort* dst = Ob + ((size_t)(b * SDIM + s)) * EDIM + h * DDIM + quad * 4;
#pragma unroll
    for (int ni = 0; ni < 4; ++ni) {
        int d0 = ni * 16 + quad * 4;
        float v0 = (o[ni][0] + E12 * Fv[d0 + 0]) * inv;
        float v1 = (o[ni][1] + E12 * Fv[d0 + 1]) * inv;
        float v2 = (o[ni][2] + E12 * Fv[d0 + 2]) * inv;
        float v3 = (o[ni][3] + E12 * Fv[d0 + 3]) * inv;
        uint2 pk;
        pk.x = pkbf2(v0, v1);
        pk.y = pkbf2(v2, v3);
        *(uint2*)(dst + ni * 16) = pk;
    }
}

extern "C" void kernel_launch(void* const* d_in, const int* in_sizes, int n_in,
                              void* d_out, int out_size, void* d_ws, size_t ws_size,
                              hipStream_t stream) {
    const float* x      = (const float*)d_in[0];
    const float* Wqkv_w = (const float*)d_in[1];
    const float* Wqkv_b = (const float*)d_in[2];
    const float* out_w  = (const float*)d_in[3];
    const float* out_b  = (const float*)d_in[4];
    const float* dd     = (const float*)d_in[5];

    char* ws = (char*)d_ws;
    const size_t MB = 1024 * 1024;
    ushort* xb    = (ushort*)(ws + 0 * MB);    // dead after gemm<1>; PS reuses it
    ushort* wqkvb = (ushort*)(ws + 8 * MB);
    ushort* owb   = (ushort*)(ws + 14 * MB);
    ushort* qkvb  = (ushort*)(ws + 16 * MB);   // q,k:[b,h,s,d] v:[b,h,d,s]
    ushort* ob    = (ushort*)(ws + 40 * MB);
    float*  PSp   = (float*)(ws + 0 * MB);     // 32*33*64*4 = 270KB (after gemm<1>)

    const int n_x = BN * SDIM * EDIM;
    const int n_w = 3 * EDIM * EDIM;
    const int n_o = EDIM * EDIM;
    const int HSD = BN * HN * SDIM * DDIM;

    to_bf16_3<<<(n_x + n_w + n_o) / 1024, 256, 0, stream>>>(
        x, xb, n_x, Wqkv_w, wqkvb, n_w, out_w, owb, n_o);

    gemm_bt<1, 4><<<dim3(32, 24), 256, 0, stream>>>(xb, wqkvb, Wqkv_b, (void*)qkvb,
                                                    BN * SDIM, 3 * EDIM, EDIM);

    vsum_prefix<<<32, 64, 0, stream>>>(qkvb + 2 * HSD, PSp);

    flash_attn<<<dim3(SDIM / 128, BN * HN), 512, 0, stream>>>(
        qkvb, qkvb + HSD, qkvb + 2 * HSD, dd, PSp, ob);

    gemm_bt<0, 2><<<dim3(64, 8), 256, 0, stream>>>(ob, owb, out_b, d_out,
                                                   BN * SDIM, EDIM, EDIM);
}

// Round 7
// 163.782 us; speedup vs baseline: 2.0178x; 1.2004x over previous
//
#include <hip/hip_runtime.h>
#include <hip/hip_bf16.h>

#define BN 2
#define SDIM 2048
#define EDIM 1024
#define HN 16
#define DDIM 64

typedef __attribute__((ext_vector_type(8))) short bfrag;
typedef __attribute__((ext_vector_type(4))) float ffrag;

__device__ __forceinline__ ffrag mfma16(bfrag a, bfrag b, ffrag c) {
    return __builtin_amdgcn_mfma_f32_16x16x32_bf16(a, b, c, 0, 0, 0);
}

__device__ __forceinline__ ushort f2bf(float f) {
    union { float f; unsigned u; } un;
    un.f = f;
    unsigned u = un.u;
    u += 0x7fffu + ((u >> 16) & 1u);   // RNE
    return (ushort)(u >> 16);
}

__device__ __forceinline__ uint pkbf2(float a, float b) {
    __hip_bfloat162 h = __float22bfloat162_rn(make_float2(a, b));
    union { __hip_bfloat162 h; uint u; } cv;
    cv.h = h;
    return cv.u;
}

// async global->LDS: 16B/lane; LDS dest = wave-uniform base + lane*16
__device__ __forceinline__ void gld16(const void* g, void* l) {
    __builtin_amdgcn_global_load_lds((const __attribute__((address_space(1))) void*)g,
                                     (__attribute__((address_space(3))) void*)l,
                                     16, 0, 0);
}

// ---------------- fused fp32 -> bf16 conversion ----------------
__global__ __launch_bounds__(256) void to_bf16_3(const float* __restrict__ a, ushort* __restrict__ oa, int na,
                                                 const float* __restrict__ b, ushort* __restrict__ ob, int nb,
                                                 const float* __restrict__ c, ushort* __restrict__ oc, int nc) {
    int i = (blockIdx.x * 256 + threadIdx.x) * 4;
    const float* src;
    ushort* dst;
    if (i < na)                { src = a + i;            dst = oa + i; }
    else if (i < na + nb)      { src = b + (i - na);     dst = ob + (i - na); }
    else if (i < na + nb + nc) { src = c + (i - na - nb); dst = oc + (i - na - nb); }
    else return;
    float4 v = *(const float4*)src;
    uint2 u;
    u.x = pkbf2(v.x, v.y);
    u.y = pkbf2(v.z, v.w);
    *(uint2*)dst = u;
}

// ---------------- bf16 BT-GEMM, BK=64, rotate-swizzled LDS, gld16 staging ----------------
// Tile: (MI*32) x 128, 4 waves (2x2), wave = (MI*16) x 64. BK=64: rows of 8
// 16B chunks; chunk c of row r stored at slot (c + r) & 7.
// MODE 0: fp32 out row-major. MODE 1: qkv scatter, V transposed to [b,h,d,s].
template <int MODE, int MI>
__global__ __launch_bounds__(256) void gemm_bt(const ushort* __restrict__ A,
                                               const ushort* __restrict__ Bt,
                                               const float* __restrict__ bias,
                                               void* __restrict__ Cout,
                                               int M, int N, int K) {
    __shared__ ushort As[MI * 32 * 64];
    __shared__ ushort Bs[128 * 64];

    const int tid  = threadIdx.x;
    const int wave = tid >> 6;
    const int lane = tid & 63;
    const int ln16 = lane & 15;
    const int quad = lane >> 4;
    const int wm = wave >> 1, wn = wave & 1;
    const int bm = blockIdx.x * (MI * 32);
    const int bn = blockIdx.y * 128;

    ffrag acc[MI][4];
#pragma unroll
    for (int mi = 0; mi < MI; ++mi)
#pragma unroll
        for (int ni = 0; ni < 4; ++ni)
            acc[mi][ni] = (ffrag){0.f, 0.f, 0.f, 0.f};

    for (int k0 = 0; k0 < K; k0 += 64) {
        // A: MI*32 rows x 8 chunks = MI*256 chunks; 256 lanes -> MI rounds
#pragma unroll
        for (int p = 0; p < MI; ++p) {
            int g0 = p * 256 + wave * 64;        // wave-uniform chunk base
            int g  = g0 + lane;
            int r  = g >> 3;
            int c  = ((g & 7) - r) & 7;          // inverse swizzle
            gld16(A + (size_t)(bm + r) * K + k0 + c * 8, (ushort*)As + g0 * 8);
        }
        // B: 128 rows x 8 chunks = 1024 chunks -> 4 rounds
#pragma unroll
        for (int p = 0; p < 4; ++p) {
            int g0 = p * 256 + wave * 64;
            int g  = g0 + lane;
            int r  = g >> 3;
            int c  = ((g & 7) - r) & 7;
            gld16(Bt + (size_t)(bn + r) * K + k0 + c * 8, (ushort*)Bs + g0 * 8);
        }
        __syncthreads();

#pragma unroll
        for (int kb = 0; kb < 2; ++kb) {
            bfrag af[MI], bf[4];
#pragma unroll
            for (int mi = 0; mi < MI; ++mi) {
                int r = wm * (MI * 16) + mi * 16 + ln16;
                af[mi] = *(const bfrag*)&As[r * 64 + ((kb * 4 + quad + r) & 7) * 8];
            }
#pragma unroll
            for (int ni = 0; ni < 4; ++ni) {
                int r = wn * 64 + ni * 16 + ln16;
                bf[ni] = *(const bfrag*)&Bs[r * 64 + ((kb * 4 + quad + r) & 7) * 8];
            }
#pragma unroll
            for (int mi = 0; mi < MI; ++mi)
#pragma unroll
                for (int ni = 0; ni < 4; ++ni)
                    acc[mi][ni] = mfma16(af[mi], bf[ni], acc[mi][ni]);
        }
        __syncthreads();
    }

#pragma unroll
    for (int mi = 0; mi < MI; ++mi) {
#pragma unroll
        for (int ni = 0; ni < 4; ++ni) {
            int col = bn + wn * 64 + ni * 16 + ln16;
            float bc = bias[col];
            int row0 = bm + wm * (MI * 16) + mi * 16 + quad * 4;
            if (MODE == 0) {
#pragma unroll
                for (int reg = 0; reg < 4; ++reg)
                    ((float*)Cout)[(size_t)(row0 + reg) * N + col] = acc[mi][ni][reg] + bc;
            } else {
                int which = col >> 10;        // wave-uniform: 0=q 1=k 2=v
                int rem = col & 1023;
                int h = rem >> 6;
                int d = rem & 63;
                int b = row0 >> 11;
                int s0 = row0 & 2047;
                if (which == 2) {
                    // V transposed [b,h,d,s]: 4 regs = 4 consecutive s -> 8B store
                    float v0 = acc[mi][ni][0] + bc, v1 = acc[mi][ni][1] + bc;
                    float v2 = acc[mi][ni][2] + bc, v3 = acc[mi][ni][3] + bc;
                    uint2 pk;
                    pk.x = pkbf2(v0, v1);
                    pk.y = pkbf2(v2, v3);
                    size_t dst = 2ull * (BN * HN * SDIM * DDIM) +
                                 (((size_t)(b * HN + h)) * DDIM + d) * SDIM + s0;
                    *(uint2*)((ushort*)Cout + dst) = pk;
                } else {
                    float sc = (which == 0) ? 0.125f : 1.f;
#pragma unroll
                    for (int reg = 0; reg < 4; ++reg) {
                        float v = (acc[mi][ni][reg] + bc) * sc;
                        size_t dst = (size_t)which * (BN * HN * SDIM * DDIM) +
                                     (((size_t)(b * HN + h)) * SDIM + s0 + reg) * DDIM + d;
                        ((ushort*)Cout)[dst] = f2bf(v);
                    }
                }
            }
        }
    }
}

// ---------------- per-head per-tile V sums (parallel) ----------------
// grid (32, 8), 256 threads = 4 tiles x 64 d. T[bh][tile][d] = sum_{s in tile} V[d][s].
// Vtb layout [b,h,d,s] -> each thread reads 64 contiguous bf16 (8 x uint4).
__global__ __launch_bounds__(256) void vsum_tiles(const ushort* __restrict__ Vtb,
                                                  float* __restrict__ T) {
    const int bh   = blockIdx.x;
    const int tile = blockIdx.y * 4 + (threadIdx.x >> 6);
    const int d    = threadIdx.x & 63;
    const ushort* row = Vtb + ((size_t)bh * DDIM + d) * SDIM + tile * 64;
    float s = 0.f;
#pragma unroll
    for (int j = 0; j < 64; j += 8) {
        uint4 v = *(const uint4*)(row + j);
        ushort tmp[8];
        *(uint4*)tmp = v;
#pragma unroll
        for (int e = 0; e < 8; ++e) {
            union { float f; uint u; } c;
            c.u = ((uint)tmp[e]) << 16;
            s += c.f;
        }
    }
    T[((size_t)bh * 32 + tile) * 64 + d] = s;
}

// ---------------- flash attention with near-band + closed-form far field ----------------
// p = exp(s*e^{-a*dist} - 12). For a*dist >= 16, p == e^{-12} to ~1e-11 abs:
// far tiles contribute e^{-12}*sum(V) (from T tile-sums) and e^{-12} each to l.
__global__ __launch_bounds__(512, 4) void flash_attn(const ushort* __restrict__ Qb,
                                                     const ushort* __restrict__ Kb,
                                                     const ushort* __restrict__ Vtb,
                                                     const float* __restrict__ decay_ptr,
                                                     const float* __restrict__ T,
                                                     ushort* __restrict__ Ob) {
    __shared__ ushort KVs[2][2][4096];   // [buf][K / Vt][64 rows x 8 chunks, swizzled]
    __shared__ ushort Pb[128][72];       // Q staging, then P exchange (per-wave rows)
    __shared__ float  Fv[64];            // far-field V sum per d

    const int tid  = threadIdx.x;
    const int wave = tid >> 6;
    const int lane = tid & 63;
    const int ln16 = lane & 15;
    const int quad = lane >> 4;

    const int bh = blockIdx.y;
    const int q0 = blockIdx.x * 128;
    const size_t head_off = (size_t)bh * SDIM * DDIM;
    const float absa = fabsf(decay_ptr[0]);
    const float LOG2E = 1.442695041f;
    const float M0L2 = -17.3123404f;     // -12 * log2(e)
    const float E12 = 6.144212353e-6f;   // e^-12

    // near band: tiles with a*min-dist(block q-range, tile) < 16
    int Dstar = (absa > 1e-5f) ? (int)ceilf(16.0f / absa) : (4 * SDIM);
    int lo = q0 - 63 - Dstar; if (lo < 0) lo = 0;
    int hi = q0 + 127 + Dstar; if (hi > SDIM - 1) hi = SDIM - 1;
    const int tlo = lo >> 6;
    const int thi = hi >> 6;
    const int ntiles = thi - tlo + 1;

    // far-field V sums from per-tile sums (overlapped with Q/K staging)
    if (tid < 64) {
        const float* Tp = T + (size_t)bh * 32 * 64;
        float s = 0.f;
        for (int k = 0; k < tlo; ++k)      s += Tp[k * 64 + tid];
        for (int k = thi + 1; k < 32; ++k) s += Tp[k * 64 + tid];
        Fv[tid] = s;
    }

    auto stageKV = [&](int t0, int buf) {
        int g0 = wave * 64;
        int g  = g0 + lane;
        int r  = g >> 3;
        int c  = (g - r) & 7;            // inverse swizzle
        gld16(Kb  + head_off + (size_t)(t0 + r) * DDIM + c * 8,
              (ushort*)&KVs[buf][0][0] + g0 * 8);
        gld16(Vtb + head_off + (size_t)r * SDIM + t0 + c * 8,
              (ushort*)&KVs[buf][1][0] + g0 * 8);
    };

    // stage Q (128x64) into Pb + first K/V tile into buf 0
#pragma unroll
    for (int p = 0; p < 2; ++p) {
        int idx = p * 512 + tid;
        int r = idx >> 3, c = (idx & 7) * 8;
        *(uint4*)&Pb[r][c] = *(const uint4*)(Qb + head_off + (size_t)(q0 + r) * DDIM + c);
    }
    stageKV(tlo * 64, 0);
    __syncthreads();

    bfrag aq[2];
#pragma unroll
    for (int kb = 0; kb < 2; ++kb)
        aq[kb] = *(const bfrag*)&Pb[wave * 16 + ln16][kb * 32 + quad * 8];

    bfrag ones;
#pragma unroll
    for (int i = 0; i < 8; ++i) ones[i] = (short)0x3F80;   // bf16 1.0

    float EcB[4], FcB[4], Epw[4], Fpw[4];
#pragma unroll
    for (int reg = 0; reg < 4; ++reg) {
        int cr = quad * 4 + reg;
        EcB[reg] = __expf(-absa * (float)(15 - cr));
        FcB[reg] = __expf(-absa * (float)cr);
    }
#pragma unroll
    for (int ni = 0; ni < 4; ++ni) {
        Epw[ni] = __expf(-absa * (float)(16 * (3 - ni)));
        Fpw[ni] = __expf(-absa * (float)(16 * ni));
    }
    const float Er = __expf(-absa * (float)ln16);
    const float Fr = __expf(-absa * (float)(15 - ln16));

    ffrag lacc = (ffrag){0.f, 0.f, 0.f, 0.f};
    ffrag o[4];
#pragma unroll
    for (int ni = 0; ni < 4; ++ni) o[ni] = (ffrag){0.f, 0.f, 0.f, 0.f};

    const int m = wave * 16 + ln16;

    for (int it = 0; it < ntiles; ++it) {
        const int t0 = (tlo + it) * 64;
        const int buf = it & 1;
        if (it + 1 < ntiles) stageKV(t0 + 64, buf ^ 1);   // async prefetch

        const ushort* Kt = &KVs[buf][0][0];
        const ushort* Vt = &KVs[buf][1][0];

        // S^T = K * Q^T
        ffrag sc[4];
#pragma unroll
        for (int ni = 0; ni < 4; ++ni) {
            ffrag a = (ffrag){0.f, 0.f, 0.f, 0.f};
            const int rk = ni * 16 + ln16;
#pragma unroll
            for (int kb = 0; kb < 2; ++kb) {
                bfrag kf = *(const bfrag*)&Kt[rk * 64 + ((kb * 4 + quad + rk) & 7) * 8];
                a = mfma16(kf, aq[kb], a);
            }
            sc[ni] = a;
        }

        // p = exp2(fma(s, decay*log2e, -12*log2e)); pack P to own-wave LDS rows
        const int ds = q0 + wave * 16 - t0;
        float hh = 0.f;
        if (ds >= 64)       hh = __expf(-absa * (float)(ds - 63)) * Er * LOG2E;
        else if (ds <= -16) hh = __expf(-absa * (float)(-ds - 15)) * Fr * LOG2E;

#pragma unroll
        for (int ni = 0; ni < 4; ++ni) {
            float f0, f1, f2, f3;
            if (ds >= 64) {
                float hn = hh * Epw[ni];
                f0 = hn * EcB[0]; f1 = hn * EcB[1]; f2 = hn * EcB[2]; f3 = hn * EcB[3];
            } else if (ds <= -16) {
                float hn = hh * Fpw[ni];
                f0 = hn * FcB[0]; f1 = hn * FcB[1]; f2 = hn * FcB[2]; f3 = hn * FcB[3];
            } else {
                int c0 = ni * 16 + quad * 4;
                f0 = __expf(-absa * fabsf((float)(ds + ln16 - c0)))     * LOG2E;
                f1 = __expf(-absa * fabsf((float)(ds + ln16 - c0 - 1))) * LOG2E;
                f2 = __expf(-absa * fabsf((float)(ds + ln16 - c0 - 2))) * LOG2E;
                f3 = __expf(-absa * fabsf((float)(ds + ln16 - c0 - 3))) * LOG2E;
            }
            float p0 = exp2f(fmaf(sc[ni][0], f0, M0L2));
            float p1 = exp2f(fmaf(sc[ni][1], f1, M0L2));
            float p2 = exp2f(fmaf(sc[ni][2], f2, M0L2));
            float p3 = exp2f(fmaf(sc[ni][3], f3, M0L2));
            uint2 pk;
            pk.x = pkbf2(p0, p1);
            pk.y = pkbf2(p2, p3);
            *(uint2*)&Pb[m][ni * 16 + quad * 4] = pk;   // own-wave rows: no barrier
        }

        bfrag ap[2];
#pragma unroll
        for (int kb = 0; kb < 2; ++kb)
            ap[kb] = *(const bfrag*)&Pb[m][kb * 32 + quad * 8];

#pragma unroll
        for (int kb = 0; kb < 2; ++kb)
            lacc = mfma16(ones, ap[kb], lacc);
#pragma unroll
        for (int ni = 0; ni < 4; ++ni) {
            const int rv = ni * 16 + ln16;
#pragma unroll
            for (int kb = 0; kb < 2; ++kb) {
                bfrag vf = *(const bfrag*)&Vt[rv * 64 + ((kb * 4 + quad + rv) & 7) * 8];
                o[ni] = mfma16(vf, ap[kb], o[ni]);
            }
        }
        __syncthreads();
    }

    // epilogue: add far field, normalize, store
    const float farl = E12 * (float)(SDIM - 64 * ntiles);
    const float inv = 1.f / (lacc[0] + farl);
    const int b = bh / HN, h = bh % HN;
    const int s = q0 + m;
    ushort* dst = Ob + ((size_t)(b * SDIM + s)) * EDIM + h * DDIM + quad * 4;
#pragma unroll
    for (int ni = 0; ni < 4; ++ni) {
        int d0 = ni * 16 + quad * 4;
        float v0 = (o[ni][0] + E12 * Fv[d0 + 0]) * inv;
        float v1 = (o[ni][1] + E12 * Fv[d0 + 1]) * inv;
        float v2 = (o[ni][2] + E12 * Fv[d0 + 2]) * inv;
        float v3 = (o[ni][3] + E12 * Fv[d0 + 3]) * inv;
        uint2 pk;
        pk.x = pkbf2(v0, v1);
        pk.y = pkbf2(v2, v3);
        *(uint2*)(dst + ni * 16) = pk;
    }
}

extern "C" void kernel_launch(void* const* d_in, const int* in_sizes, int n_in,
                              void* d_out, int out_size, void* d_ws, size_t ws_size,
                              hipStream_t stream) {
    const float* x      = (const float*)d_in[0];
    const float* Wqkv_w = (const float*)d_in[1];
    const float* Wqkv_b = (const float*)d_in[2];
    const float* out_w  = (const float*)d_in[3];
    const float* out_b  = (const float*)d_in[4];
    const float* dd     = (const float*)d_in[5];

    char* ws = (char*)d_ws;
    const size_t MB = 1024 * 1024;
    ushort* xb    = (ushort*)(ws + 0 * MB);    // dead after gemm<1>; T reuses it
    ushort* wqkvb = (ushort*)(ws + 8 * MB);
    ushort* owb   = (ushort*)(ws + 14 * MB);
    ushort* qkvb  = (ushort*)(ws + 16 * MB);   // q,k:[b,h,s,d] v:[b,h,d,s]
    ushort* ob    = (ushort*)(ws + 40 * MB);
    float*  Tp    = (float*)(ws + 0 * MB);     // 32*32*64*4 = 256 KB (after gemm<1>)

    const int n_x = BN * SDIM * EDIM;
    const int n_w = 3 * EDIM * EDIM;
    const int n_o = EDIM * EDIM;
    const int HSD = BN * HN * SDIM * DDIM;

    to_bf16_3<<<(n_x + n_w + n_o) / 1024, 256, 0, stream>>>(
        x, xb, n_x, Wqkv_w, wqkvb, n_w, out_w, owb, n_o);

    gemm_bt<1, 4><<<dim3(32, 24), 256, 0, stream>>>(xb, wqkvb, Wqkv_b, (void*)qkvb,
                                                    BN * SDIM, 3 * EDIM, EDIM);

    vsum_tiles<<<dim3(32, 8), 256, 0, stream>>>(qkvb + 2 * HSD, Tp);

    flash_attn<<<dim3(SDIM / 128, BN * HN), 512, 0, stream>>>(
        qkvb, qkvb + HSD, qkvb + 2 * HSD, dd, Tp, ob);

    gemm_bt<0, 2><<<dim3(64, 8), 256, 0, stream>>>(ob, owb, out_b, d_out,
                                                   BN * SDIM, EDIM, EDIM);
}